// Round 1
// baseline (2333.974 us; speedup 1.0000x reference)
//
#include <hip/hip_runtime.h>
#include <math.h>

#define N_NODES 50000
#define E_EDGES 800000
#define IN_DIM 128
#define HEADS 4
#define OUT_DIM 32
#define HD 128          // HEADS*OUT_DIM
#define LEAKY 0.4f
#define BN_EPS 1e-5f

// ---- monotonic float<->uint encoding for atomicMax on floats ----
__device__ __forceinline__ unsigned enc_max(float f) {
    unsigned u = __float_as_uint(f);
    return ((int)u >= 0) ? (u | 0x80000000u) : ~u;
}
__device__ __forceinline__ float dec_max(unsigned u) {
    return (u & 0x80000000u) ? __uint_as_float(u ^ 0x80000000u)
                             : __uint_as_float(~u);
}

__device__ __forceinline__ float leaky(float v) {
    return v > 0.f ? v : LEAKY * v;
}

// ============================================================
// K1: h = x @ W  (N x 128 @ 128 x 128), fused s = h.a_src, t = h.a_tgt
// block = 256 threads; each block does 16 rows x 128 cols.
// W (64KB) staged in LDS; x row reads are wave-uniform (scalar-load friendly).
// ============================================================
#define K1_ROWS 16
__global__ __launch_bounds__(256) void k1_gemm(
    const float* __restrict__ x, const float* __restrict__ W,
    const float* __restrict__ a_src, const float* __restrict__ a_tgt,
    float* __restrict__ h, float* __restrict__ s, float* __restrict__ t)
{
    __shared__ float Wl[IN_DIM * HD];   // 64 KB
    for (int i = threadIdx.x; i < IN_DIM * HD; i += 256) Wl[i] = W[i];
    __syncthreads();

    const int c    = threadIdx.x & 127;          // output column
    const int half = threadIdx.x >> 7;           // 0/1: row sub-group
    const int row0 = blockIdx.x * K1_ROWS + half * (K1_ROWS / 2);
    const int head = c >> 5;
    const int d    = c & 31;
    const float as = a_src[head * OUT_DIM + d];
    const float at = a_tgt[head * OUT_DIM + d];

    float acc[K1_ROWS / 2];
#pragma unroll
    for (int r = 0; r < K1_ROWS / 2; r++) acc[r] = 0.f;

    const float* xb = x + (size_t)row0 * IN_DIM;
    for (int k = 0; k < IN_DIM; k++) {
        float w = Wl[k * HD + c];
#pragma unroll
        for (int r = 0; r < K1_ROWS / 2; r++)
            acc[r] = fmaf(xb[r * IN_DIM + k], w, acc[r]);
    }

#pragma unroll
    for (int r = 0; r < K1_ROWS / 2; r++)
        h[(size_t)(row0 + r) * HD + c] = acc[r];

    // 32-lane reductions over d for s,t (xor masks < 32 stay in head group)
#pragma unroll
    for (int r = 0; r < K1_ROWS / 2; r++) {
        float ps = acc[r] * as;
        float pt = acc[r] * at;
#pragma unroll
        for (int m = 16; m >= 1; m >>= 1) {
            ps += __shfl_xor(ps, m, 64);
            pt += __shfl_xor(pt, m, 64);
        }
        if (d == 0) {
            s[(row0 + r) * HEADS + head] = ps;
            t[(row0 + r) * HEADS + head] = pt;
        }
    }
}

// ============================================================
// K2: global per-head max of leaky(s[src]+t[tgt]) over all edges
// ============================================================
__global__ __launch_bounds__(256) void k2_max(
    const int* __restrict__ src, const int* __restrict__ tgt,
    const float* __restrict__ s, const float* __restrict__ t,
    unsigned* __restrict__ hmax)
{
    int e = blockIdx.x * 256 + threadIdx.x;
    float m0 = -INFINITY, m1 = -INFINITY, m2 = -INFINITY, m3 = -INFINITY;
    if (e < E_EDGES) {
        int si = src[e], ti = tgt[e];
        float4 s4 = ((const float4*)s)[si];
        float4 t4 = ((const float4*)t)[ti];
        m0 = leaky(s4.x + t4.x);
        m1 = leaky(s4.y + t4.y);
        m2 = leaky(s4.z + t4.z);
        m3 = leaky(s4.w + t4.w);
    }
#pragma unroll
    for (int m = 32; m >= 1; m >>= 1) {
        m0 = fmaxf(m0, __shfl_xor(m0, m, 64));
        m1 = fmaxf(m1, __shfl_xor(m1, m, 64));
        m2 = fmaxf(m2, __shfl_xor(m2, m, 64));
        m3 = fmaxf(m3, __shfl_xor(m3, m, 64));
    }
    if ((threadIdx.x & 63) == 0) {
        atomicMax(&hmax[0], enc_max(m0));
        atomicMax(&hmax[1], enc_max(m1));
        atomicMax(&hmax[2], enc_max(m2));
        atomicMax(&hmax[3], enc_max(m3));
    }
}

// ============================================================
// K3: alpha = exp(e - max); alpha_sum[tgt] += alpha
// ============================================================
__global__ __launch_bounds__(256) void k3_alpha(
    const int* __restrict__ src, const int* __restrict__ tgt,
    const float* __restrict__ s, const float* __restrict__ t,
    const unsigned* __restrict__ hmax,
    float* __restrict__ alpha, float* __restrict__ asum)
{
    int e = blockIdx.x * 256 + threadIdx.x;
    if (e >= E_EDGES) return;
    float mx0 = dec_max(hmax[0]);
    float mx1 = dec_max(hmax[1]);
    float mx2 = dec_max(hmax[2]);
    float mx3 = dec_max(hmax[3]);
    int si = src[e], ti = tgt[e];
    float4 s4 = ((const float4*)s)[si];
    float4 t4 = ((const float4*)t)[ti];
    float4 a;
    a.x = __expf(leaky(s4.x + t4.x) - mx0);
    a.y = __expf(leaky(s4.y + t4.y) - mx1);
    a.z = __expf(leaky(s4.z + t4.z) - mx2);
    a.w = __expf(leaky(s4.w + t4.w) - mx3);
    ((float4*)alpha)[e] = a;
    float* as4 = asum + (size_t)ti * 4;
    unsafeAtomicAdd(as4 + 0, a.x);
    unsafeAtomicAdd(as4 + 1, a.y);
    unsafeAtomicAdd(as4 + 2, a.z);
    unsafeAtomicAdd(as4 + 3, a.w);
}

// ============================================================
// K4: out_pre[tgt] += h[src] * alpha/(asum[tgt]+1e-16)
// 32 lanes per edge, float4 per lane (128 channels).
// ============================================================
__global__ __launch_bounds__(256) void k4_aggr(
    const int* __restrict__ src, const int* __restrict__ tgt,
    const float* __restrict__ h, const float* __restrict__ alpha,
    const float* __restrict__ asum, float* __restrict__ outp)
{
    long long g = (long long)blockIdx.x * 256 + threadIdx.x;
    int e    = (int)(g >> 5);
    int lane = (int)(g & 31);
    if (e >= E_EDGES) return;
    int si = src[e], ti = tgt[e];
    int head = lane >> 3;
    float a  = alpha[(size_t)e * 4 + head];
    float sm = asum[(size_t)ti * 4 + head];
    float w  = a / (sm + 1e-16f);
    float4 hv = ((const float4*)h)[(size_t)si * 32 + lane];
    float* o = outp + (size_t)ti * HD + lane * 4;
    unsafeAtomicAdd(o + 0, hv.x * w);
    unsafeAtomicAdd(o + 1, hv.y * w);
    unsafeAtomicAdd(o + 2, hv.z * w);
    unsafeAtomicAdd(o + 3, hv.w * w);
}

// ============================================================
// K5: BN stats: per-channel sum & sumsq over N rows
// block covers 128 rows; thread = (channel, half)
// ============================================================
__global__ __launch_bounds__(256) void k5_stats(
    const float* __restrict__ outp,
    float* __restrict__ bnsum, float* __restrict__ bnsq)
{
    int c    = threadIdx.x & 127;
    int half = threadIdx.x >> 7;
    int base = blockIdx.x * 128;
    int end  = min(base + 128, N_NODES);
    float sm = 0.f, sq = 0.f;
    for (int r = base + half; r < end; r += 2) {
        float v = outp[(size_t)r * HD + c];
        sm += v;
        sq = fmaf(v, v, sq);
    }
    unsafeAtomicAdd(&bnsum[c], sm);
    unsafeAtomicAdd(&bnsq[c], sq);
}

// ============================================================
// K6: BN apply -> d_out
// ============================================================
__global__ __launch_bounds__(256) void k6_apply(
    const float* __restrict__ outp,
    const float* __restrict__ bnsum, const float* __restrict__ bnsq,
    const float* __restrict__ gamma, const float* __restrict__ beta,
    float* __restrict__ out)
{
    int c    = threadIdx.x & 127;
    int half = threadIdx.x >> 7;
    int base = blockIdx.x * 128;
    int end  = min(base + 128, N_NODES);
    float inv_n = 1.0f / (float)N_NODES;
    float mean = bnsum[c] * inv_n;
    float var  = bnsq[c] * inv_n - mean * mean;
    float scale = gamma[c] * rsqrtf(var + BN_EPS);
    float shift = beta[c] - mean * scale;
    for (int r = base + half; r < end; r += 2) {
        size_t i = (size_t)r * HD + c;
        out[i] = fmaf(outp[i], scale, shift);
    }
}

// ============================================================
extern "C" void kernel_launch(void* const* d_in, const int* in_sizes, int n_in,
                              void* d_out, int out_size, void* d_ws, size_t ws_size,
                              hipStream_t stream)
{
    const float* x     = (const float*)d_in[0];
    const float* W     = (const float*)d_in[1];
    const float* a_src = (const float*)d_in[2];
    const float* a_tgt = (const float*)d_in[3];
    const float* gamma = (const float*)d_in[4];
    const float* beta  = (const float*)d_in[5];
    const int*   eidx  = (const int*)d_in[6];
    const int* src = eidx;
    const int* tgt = eidx + E_EDGES;
    float* out = (float*)d_out;

    // workspace layout (floats)
    float* h     = (float*)d_ws;                  // 6,400,000
    float* s     = h + (size_t)N_NODES * HD;      //   200,000
    float* t     = s + (size_t)N_NODES * HEADS;   //   200,000
    float* alpha = t + (size_t)N_NODES * HEADS;   // 3,200,000
    // ---- zero-init region (single memset) ----
    float*    asum  = alpha + (size_t)E_EDGES * HEADS;   //   200,000
    float*    outp  = asum + (size_t)N_NODES * HEADS;    // 6,400,000
    unsigned* hmax  = (unsigned*)(outp + (size_t)N_NODES * HD); // 16 (4 used)
    float*    bnsum = (float*)(hmax + 16);               // 128
    float*    bnsq  = bnsum + HD;                        // 128
    size_t zero_bytes = ((size_t)N_NODES * HEADS + (size_t)N_NODES * HD
                         + 16 + HD + HD) * sizeof(float);
    hipMemsetAsync(asum, 0, zero_bytes, stream);

    // K1: GEMM + s,t   (50000/16 = 3125 blocks exactly)
    k1_gemm<<<N_NODES / K1_ROWS, 256, 0, stream>>>(x, W, a_src, a_tgt, h, s, t);
    // K2: global per-head max (800000/256 = 3125 exactly)
    k2_max<<<(E_EDGES + 255) / 256, 256, 0, stream>>>(src, tgt, s, t, hmax);
    // K3: alpha + segment sum
    k3_alpha<<<(E_EDGES + 255) / 256, 256, 0, stream>>>(src, tgt, s, t, hmax,
                                                        alpha, asum);
    // K4: scatter aggregation (E*32 threads)
    long long k4_threads = (long long)E_EDGES * 32;
    k4_aggr<<<(unsigned)((k4_threads + 255) / 256), 256, 0, stream>>>(
        src, tgt, h, alpha, asum, outp);
    // K5: BN stats
    k5_stats<<<(N_NODES + 127) / 128, 256, 0, stream>>>(outp, bnsum, bnsq);
    // K6: BN apply
    k6_apply<<<(N_NODES + 127) / 128, 256, 0, stream>>>(outp, bnsum, bnsq,
                                                        gamma, beta, out);
}

// Round 2
// 1079.995 us; speedup vs baseline: 2.1611x; 2.1611x over previous
//
#include <hip/hip_runtime.h>
#include <math.h>

#define N_NODES 50000
#define E_EDGES 800000
#define IN_DIM 128
#define HEADS 4
#define OUT_DIM 32
#define HD 128          // HEADS*OUT_DIM
#define LEAKY 0.4f
#define BN_EPS 1e-5f

// ---- monotonic float<->uint encoding for atomicMax on floats ----
__device__ __forceinline__ unsigned enc_max(float f) {
    unsigned u = __float_as_uint(f);
    return ((int)u >= 0) ? (u | 0x80000000u) : ~u;
}
__device__ __forceinline__ float dec_max(unsigned u) {
    return (u & 0x80000000u) ? __uint_as_float(u ^ 0x80000000u)
                             : __uint_as_float(~u);
}

__device__ __forceinline__ float leaky(float v) {
    return v > 0.f ? v : LEAKY * v;
}

// ============================================================
// CSR build: count incoming edges per target
// ============================================================
__global__ __launch_bounds__(256) void kc_count(
    const int* __restrict__ tgt, int* __restrict__ deg)
{
    int e = blockIdx.x * 256 + threadIdx.x;
    if (e < E_EDGES) atomicAdd(&deg[tgt[e]], 1);
}

// ============================================================
// CSR build: single-block exclusive scan of deg -> rowptr (+copy to wptr)
// 1024 threads, each handles a 49-element chunk.
// ============================================================
#define SCAN_T 1024
#define CHUNK ((N_NODES + SCAN_T - 1) / SCAN_T)   // 49
__global__ __launch_bounds__(SCAN_T) void kc_scan(
    const int* __restrict__ deg, int* __restrict__ rowptr, int* __restrict__ wptr)
{
    __shared__ int wsum[SCAN_T / 64];
    int th   = threadIdx.x;
    int beg  = th * CHUNK;
    int end  = min(beg + CHUNK, N_NODES);
    int sum = 0;
    for (int i = beg; i < end; i++) sum += deg[i];

    int lane = th & 63, wid = th >> 6;
    int v = sum;
#pragma unroll
    for (int off = 1; off < 64; off <<= 1) {
        int u = __shfl_up(v, off, 64);
        if (lane >= off) v += u;
    }
    if (lane == 63) wsum[wid] = v;
    __syncthreads();
    int woff = 0;
    for (int w = 0; w < wid; w++) woff += wsum[w];
    int run = woff + (v - sum);       // global exclusive prefix of this chunk
    for (int i = beg; i < end; i++) {
        rowptr[i] = run;
        wptr[i]   = run;
        run += deg[i];
    }
}

// ============================================================
// CSR build: fill source-node list in CSR order (atomic cursor).
// After this, wptr[n] == rowptr[n] + deg[n] (end pointer).
// ============================================================
__global__ __launch_bounds__(256) void kc_fill(
    const int* __restrict__ src, const int* __restrict__ tgt,
    int* __restrict__ wptr, int* __restrict__ esrc)
{
    int e = blockIdx.x * 256 + threadIdx.x;
    if (e >= E_EDGES) return;
    int pos = atomicAdd(&wptr[tgt[e]], 1);
    esrc[pos] = src[e];
}

// ============================================================
// K1: h = x @ W  (N x 128 @ 128 x 128), fused s = h.a_src, t = h.a_tgt
// ============================================================
#define K1_ROWS 16
__global__ __launch_bounds__(256) void k1_gemm(
    const float* __restrict__ x, const float* __restrict__ W,
    const float* __restrict__ a_src, const float* __restrict__ a_tgt,
    float* __restrict__ h, float* __restrict__ s, float* __restrict__ t)
{
    __shared__ float Wl[IN_DIM * HD];   // 64 KB
    for (int i = threadIdx.x; i < IN_DIM * HD; i += 256) Wl[i] = W[i];
    __syncthreads();

    const int c    = threadIdx.x & 127;
    const int half = threadIdx.x >> 7;
    const int row0 = blockIdx.x * K1_ROWS + half * (K1_ROWS / 2);
    const int head = c >> 5;
    const int d    = c & 31;
    const float as = a_src[head * OUT_DIM + d];
    const float at = a_tgt[head * OUT_DIM + d];

    float acc[K1_ROWS / 2];
#pragma unroll
    for (int r = 0; r < K1_ROWS / 2; r++) acc[r] = 0.f;

    const float* xb = x + (size_t)row0 * IN_DIM;
    for (int k = 0; k < IN_DIM; k++) {
        float w = Wl[k * HD + c];
#pragma unroll
        for (int r = 0; r < K1_ROWS / 2; r++)
            acc[r] = fmaf(xb[r * IN_DIM + k], w, acc[r]);
    }

#pragma unroll
    for (int r = 0; r < K1_ROWS / 2; r++)
        h[(size_t)(row0 + r) * HD + c] = acc[r];

#pragma unroll
    for (int r = 0; r < K1_ROWS / 2; r++) {
        float ps = acc[r] * as;
        float pt = acc[r] * at;
#pragma unroll
        for (int m = 16; m >= 1; m >>= 1) {
            ps += __shfl_xor(ps, m, 64);
            pt += __shfl_xor(pt, m, 64);
        }
        if (d == 0) {
            s[(row0 + r) * HEADS + head] = ps;
            t[(row0 + r) * HEADS + head] = pt;
        }
    }
}

// ============================================================
// K2: global per-head max of leaky(s[src]+t[tgt]) over all edges
// ============================================================
__global__ __launch_bounds__(256) void k2_max(
    const int* __restrict__ src, const int* __restrict__ tgt,
    const float* __restrict__ s, const float* __restrict__ t,
    unsigned* __restrict__ hmax)
{
    int e = blockIdx.x * 256 + threadIdx.x;
    float m0 = -INFINITY, m1 = -INFINITY, m2 = -INFINITY, m3 = -INFINITY;
    if (e < E_EDGES) {
        int si = src[e], ti = tgt[e];
        float4 s4 = ((const float4*)s)[si];
        float4 t4 = ((const float4*)t)[ti];
        m0 = leaky(s4.x + t4.x);
        m1 = leaky(s4.y + t4.y);
        m2 = leaky(s4.z + t4.z);
        m3 = leaky(s4.w + t4.w);
    }
#pragma unroll
    for (int m = 32; m >= 1; m >>= 1) {
        m0 = fmaxf(m0, __shfl_xor(m0, m, 64));
        m1 = fmaxf(m1, __shfl_xor(m1, m, 64));
        m2 = fmaxf(m2, __shfl_xor(m2, m, 64));
        m3 = fmaxf(m3, __shfl_xor(m3, m, 64));
    }
    if ((threadIdx.x & 63) == 0) {
        atomicMax(&hmax[0], enc_max(m0));
        atomicMax(&hmax[1], enc_max(m1));
        atomicMax(&hmax[2], enc_max(m2));
        atomicMax(&hmax[3], enc_max(m3));
    }
}

// ============================================================
// K4: pull aggregation. 32 lanes per target node (float4 each = 128 ch).
// alpha computed inline; softmax denominator accumulated in-register.
// No atomics, coalesced stores.
// ============================================================
__global__ __launch_bounds__(256) void k4_pull(
    const int* __restrict__ rowptr, const int* __restrict__ wptr,
    const int* __restrict__ esrc,
    const float* __restrict__ s, const float* __restrict__ t,
    const unsigned* __restrict__ hmax,
    const float* __restrict__ h, float* __restrict__ outp)
{
    long long g = (long long)blockIdx.x * 256 + threadIdx.x;
    int node = (int)(g >> 5);
    int lane = (int)(g & 31);
    if (node >= N_NODES) return;
    int head = lane >> 3;
    int beg = rowptr[node];
    int end = wptr[node];          // rowptr[node] + deg[node]
    float mx = dec_max(hmax[head]);
    float tv = t[node * HEADS + head];

    float ax = 0.f, ay = 0.f, az = 0.f, aw = 0.f, asum = 0.f;
    for (int j = beg; j < end; j++) {
        int si  = esrc[j];                       // broadcast within group
        float sv = s[si * HEADS + head];
        float a  = __expf(leaky(sv + tv) - mx);
        float4 hv = ((const float4*)h)[(size_t)si * 32 + lane];
        ax = fmaf(a, hv.x, ax);
        ay = fmaf(a, hv.y, ay);
        az = fmaf(a, hv.z, az);
        aw = fmaf(a, hv.w, aw);
        asum += a;
    }
    float w = 1.0f / (asum + 1e-16f);
    float4 o = make_float4(ax * w, ay * w, az * w, aw * w);
    ((float4*)outp)[(size_t)node * 32 + lane] = o;
}

// ============================================================
// K5: BN stats: per-channel sum & sumsq over N rows
// ============================================================
__global__ __launch_bounds__(256) void k5_stats(
    const float* __restrict__ outp,
    float* __restrict__ bnsum, float* __restrict__ bnsq)
{
    int c    = threadIdx.x & 127;
    int half = threadIdx.x >> 7;
    int base = blockIdx.x * 128;
    int end  = min(base + 128, N_NODES);
    float sm = 0.f, sq = 0.f;
    for (int r = base + half; r < end; r += 2) {
        float v = outp[(size_t)r * HD + c];
        sm += v;
        sq = fmaf(v, v, sq);
    }
    unsafeAtomicAdd(&bnsum[c], sm);
    unsafeAtomicAdd(&bnsq[c], sq);
}

// ============================================================
// K6: BN apply -> d_out
// ============================================================
__global__ __launch_bounds__(256) void k6_apply(
    const float* __restrict__ outp,
    const float* __restrict__ bnsum, const float* __restrict__ bnsq,
    const float* __restrict__ gamma, const float* __restrict__ beta,
    float* __restrict__ out)
{
    int c    = threadIdx.x & 127;
    int half = threadIdx.x >> 7;
    int base = blockIdx.x * 128;
    int end  = min(base + 128, N_NODES);
    float inv_n = 1.0f / (float)N_NODES;
    float mean = bnsum[c] * inv_n;
    float var  = bnsq[c] * inv_n - mean * mean;
    float scale = gamma[c] * rsqrtf(var + BN_EPS);
    float shift = beta[c] - mean * scale;
    for (int r = base + half; r < end; r += 2) {
        size_t i = (size_t)r * HD + c;
        out[i] = fmaf(outp[i], scale, shift);
    }
}

// ============================================================
extern "C" void kernel_launch(void* const* d_in, const int* in_sizes, int n_in,
                              void* d_out, int out_size, void* d_ws, size_t ws_size,
                              hipStream_t stream)
{
    const float* x     = (const float*)d_in[0];
    const float* W     = (const float*)d_in[1];
    const float* a_src = (const float*)d_in[2];
    const float* a_tgt = (const float*)d_in[3];
    const float* gamma = (const float*)d_in[4];
    const float* beta  = (const float*)d_in[5];
    const int*   eidx  = (const int*)d_in[6];
    const int* src = eidx;
    const int* tgt = eidx + E_EDGES;
    float* out = (float*)d_out;

    // workspace layout (4-byte words)
    float* h      = (float*)d_ws;                       // 6,400,000
    float* s      = h + (size_t)N_NODES * HD;           //   200,000
    float* t      = s + (size_t)N_NODES * HEADS;        //   200,000
    float* outp   = t + (size_t)N_NODES * HEADS;        // 6,400,000
    int*   esrc   = (int*)(outp + (size_t)N_NODES * HD);//   800,000
    int*   rowptr = esrc + E_EDGES;                     //    50,000
    int*   wptr   = rowptr + N_NODES;                   //    50,000
    // ---- zero-init region (single memset) ----
    int*      deg   = wptr + N_NODES;                   //    50,000
    unsigned* hmax  = (unsigned*)(deg + N_NODES);       //        16
    float*    bnsum = (float*)(hmax + 16);              //       128
    float*    bnsq  = bnsum + HD;                       //       128
    size_t zero_bytes = ((size_t)N_NODES + 16 + HD + HD) * 4;
    hipMemsetAsync(deg, 0, zero_bytes, stream);

    // CSR build
    kc_count<<<(E_EDGES + 255) / 256, 256, 0, stream>>>(tgt, deg);
    kc_scan<<<1, SCAN_T, 0, stream>>>(deg, rowptr, wptr);
    kc_fill<<<(E_EDGES + 255) / 256, 256, 0, stream>>>(src, tgt, wptr, esrc);

    // GEMM + logits
    k1_gemm<<<N_NODES / K1_ROWS, 256, 0, stream>>>(x, W, a_src, a_tgt, h, s, t);
    // global per-head max
    k2_max<<<(E_EDGES + 255) / 256, 256, 0, stream>>>(src, tgt, s, t, hmax);
    // pull aggregation (no atomics)
    long long k4_threads = (long long)N_NODES * 32;
    k4_pull<<<(unsigned)((k4_threads + 255) / 256), 256, 0, stream>>>(
        rowptr, wptr, esrc, s, t, hmax, h, outp);
    // BN
    k5_stats<<<(N_NODES + 127) / 128, 256, 0, stream>>>(outp, bnsum, bnsq);
    k6_apply<<<(N_NODES + 127) / 128, 256, 0, stream>>>(outp, bnsum, bnsq,
                                                        gamma, beta, out);
}

// Round 3
// 517.026 us; speedup vs baseline: 4.5142x; 2.0889x over previous
//
#include <hip/hip_runtime.h>
#include <math.h>

#define N_NODES 50000
#define E_EDGES 800000
#define IN_DIM 128
#define HEADS 4
#define OUT_DIM 32
#define HD 128          // HEADS*OUT_DIM
#define LEAKY 0.4f
#define BN_EPS 1e-5f

// ---- monotonic float<->uint encoding for atomicMax on floats ----
// enc is order-preserving; enc(x) > 0 for all x >= -inf, so memset-0 is the
// identity element for atomicMax.
__device__ __forceinline__ unsigned enc_max(float f) {
    unsigned u = __float_as_uint(f);
    return ((int)u >= 0) ? (u | 0x80000000u) : ~u;
}
__device__ __forceinline__ float dec_max(unsigned u) {
    return (u & 0x80000000u) ? __uint_as_float(u ^ 0x80000000u)
                             : __uint_as_float(~u);
}

__device__ __forceinline__ float leaky(float v) {
    return v > 0.f ? v : LEAKY * v;
}

// ============================================================
// CSR build: count incoming edges per target
// ============================================================
__global__ __launch_bounds__(256) void kc_count(
    const int* __restrict__ tgt, int* __restrict__ deg)
{
    int e = blockIdx.x * 256 + threadIdx.x;
    if (e < E_EDGES) atomicAdd(&deg[tgt[e]], 1);
}

// ============================================================
// CSR build: single-block exclusive scan of deg -> rowptr (+copy to wptr)
// ============================================================
#define SCAN_T 1024
#define CHUNK ((N_NODES + SCAN_T - 1) / SCAN_T)   // 49
__global__ __launch_bounds__(SCAN_T) void kc_scan(
    const int* __restrict__ deg, int* __restrict__ rowptr, int* __restrict__ wptr)
{
    __shared__ int wsum[SCAN_T / 64];
    int th   = threadIdx.x;
    int beg  = th * CHUNK;
    int end  = min(beg + CHUNK, N_NODES);
    int sum = 0;
    for (int i = beg; i < end; i++) sum += deg[i];

    int lane = th & 63, wid = th >> 6;
    int v = sum;
#pragma unroll
    for (int off = 1; off < 64; off <<= 1) {
        int u = __shfl_up(v, off, 64);
        if (lane >= off) v += u;
    }
    if (lane == 63) wsum[wid] = v;
    __syncthreads();
    int woff = 0;
    for (int w = 0; w < wid; w++) woff += wsum[w];
    int run = woff + (v - sum);       // global exclusive prefix of this chunk
    for (int i = beg; i < end; i++) {
        rowptr[i] = run;
        wptr[i]   = run;
        run += deg[i];
    }
}

// ============================================================
// CSR build: fill source-node list in CSR order (atomic cursor).
// ============================================================
__global__ __launch_bounds__(256) void kc_fill(
    const int* __restrict__ src, const int* __restrict__ tgt,
    int* __restrict__ wptr, int* __restrict__ esrc)
{
    int e = blockIdx.x * 256 + threadIdx.x;
    if (e >= E_EDGES) return;
    int pos = atomicAdd(&wptr[tgt[e]], 1);
    esrc[pos] = src[e];
}

// ============================================================
// K1: h = x @ W  (N x 128 @ 128 x 128), fused s = h.a_src, t = h.a_tgt
// ============================================================
#define K1_ROWS 16
__global__ __launch_bounds__(256) void k1_gemm(
    const float* __restrict__ x, const float* __restrict__ W,
    const float* __restrict__ a_src, const float* __restrict__ a_tgt,
    float* __restrict__ h, float* __restrict__ s, float* __restrict__ t)
{
    __shared__ float Wl[IN_DIM * HD];   // 64 KB
    for (int i = threadIdx.x; i < IN_DIM * HD; i += 256) Wl[i] = W[i];
    __syncthreads();

    const int c    = threadIdx.x & 127;
    const int half = threadIdx.x >> 7;
    const int row0 = blockIdx.x * K1_ROWS + half * (K1_ROWS / 2);
    const int head = c >> 5;
    const int d    = c & 31;
    const float as = a_src[head * OUT_DIM + d];
    const float at = a_tgt[head * OUT_DIM + d];

    float acc[K1_ROWS / 2];
#pragma unroll
    for (int r = 0; r < K1_ROWS / 2; r++) acc[r] = 0.f;

    const float* xb = x + (size_t)row0 * IN_DIM;
    for (int k = 0; k < IN_DIM; k++) {
        float w = Wl[k * HD + c];
#pragma unroll
        for (int r = 0; r < K1_ROWS / 2; r++)
            acc[r] = fmaf(xb[r * IN_DIM + k], w, acc[r]);
    }

#pragma unroll
    for (int r = 0; r < K1_ROWS / 2; r++)
        h[(size_t)(row0 + r) * HD + c] = acc[r];

#pragma unroll
    for (int r = 0; r < K1_ROWS / 2; r++) {
        float ps = acc[r] * as;
        float pt = acc[r] * at;
#pragma unroll
        for (int m = 16; m >= 1; m >>= 1) {
            ps += __shfl_xor(ps, m, 64);
            pt += __shfl_xor(pt, m, 64);
        }
        if (d == 0) {
            s[(row0 + r) * HEADS + head] = ps;
            t[(row0 + r) * HEADS + head] = pt;
        }
    }
}

// ============================================================
// K2: per-head max over NODES of s and t separately.
// leaky(max_n s + max_n t) is an upper bound on the edge max; the softmax
// shift cancels between numerator and denominator, so a bound is exact
// up to fp rounding. 32 blocks -> only 256 total atomics.
// ============================================================
#define K2_BLOCKS 32
__global__ __launch_bounds__(256) void k2_nodemax(
    const float* __restrict__ s, const float* __restrict__ t,
    unsigned* __restrict__ smax, unsigned* __restrict__ tmax)
{
    float sm0 = -INFINITY, sm1 = -INFINITY, sm2 = -INFINITY, sm3 = -INFINITY;
    float tm0 = -INFINITY, tm1 = -INFINITY, tm2 = -INFINITY, tm3 = -INFINITY;
    for (int n = blockIdx.x * 256 + threadIdx.x; n < N_NODES;
         n += K2_BLOCKS * 256) {
        float4 s4 = ((const float4*)s)[n];
        float4 t4 = ((const float4*)t)[n];
        sm0 = fmaxf(sm0, s4.x); sm1 = fmaxf(sm1, s4.y);
        sm2 = fmaxf(sm2, s4.z); sm3 = fmaxf(sm3, s4.w);
        tm0 = fmaxf(tm0, t4.x); tm1 = fmaxf(tm1, t4.y);
        tm2 = fmaxf(tm2, t4.z); tm3 = fmaxf(tm3, t4.w);
    }
#pragma unroll
    for (int m = 32; m >= 1; m >>= 1) {
        sm0 = fmaxf(sm0, __shfl_xor(sm0, m, 64));
        sm1 = fmaxf(sm1, __shfl_xor(sm1, m, 64));
        sm2 = fmaxf(sm2, __shfl_xor(sm2, m, 64));
        sm3 = fmaxf(sm3, __shfl_xor(sm3, m, 64));
        tm0 = fmaxf(tm0, __shfl_xor(tm0, m, 64));
        tm1 = fmaxf(tm1, __shfl_xor(tm1, m, 64));
        tm2 = fmaxf(tm2, __shfl_xor(tm2, m, 64));
        tm3 = fmaxf(tm3, __shfl_xor(tm3, m, 64));
    }
    __shared__ float red[4][8];
    int wid = threadIdx.x >> 6;
    if ((threadIdx.x & 63) == 0) {
        red[wid][0] = sm0; red[wid][1] = sm1; red[wid][2] = sm2; red[wid][3] = sm3;
        red[wid][4] = tm0; red[wid][5] = tm1; red[wid][6] = tm2; red[wid][7] = tm3;
    }
    __syncthreads();
    if (threadIdx.x < 8) {
        float v = fmaxf(fmaxf(red[0][threadIdx.x], red[1][threadIdx.x]),
                        fmaxf(red[2][threadIdx.x], red[3][threadIdx.x]));
        unsigned* dst = (threadIdx.x < 4) ? &smax[threadIdx.x]
                                          : &tmax[threadIdx.x - 4];
        atomicMax(dst, enc_max(v));
    }
}

// ============================================================
// K4: pull aggregation. 32 lanes per target node (float4 each = 128 ch).
// ============================================================
__global__ __launch_bounds__(256) void k4_pull(
    const int* __restrict__ rowptr, const int* __restrict__ wptr,
    const int* __restrict__ esrc,
    const float* __restrict__ s, const float* __restrict__ t,
    const unsigned* __restrict__ smax, const unsigned* __restrict__ tmax,
    const float* __restrict__ h, float* __restrict__ outp)
{
    long long g = (long long)blockIdx.x * 256 + threadIdx.x;
    int node = (int)(g >> 5);
    int lane = (int)(g & 31);
    if (node >= N_NODES) return;
    int head = lane >> 3;
    int beg = rowptr[node];
    int end = wptr[node];          // rowptr[node] + deg[node]
    float mx = leaky(dec_max(smax[head]) + dec_max(tmax[head]));
    float tv = t[node * HEADS + head];

    float ax = 0.f, ay = 0.f, az = 0.f, aw = 0.f, asum = 0.f;
    for (int j = beg; j < end; j++) {
        int si  = esrc[j];                       // broadcast within group
        float sv = s[si * HEADS + head];
        float a  = __expf(leaky(sv + tv) - mx);
        float4 hv = ((const float4*)h)[(size_t)si * 32 + lane];
        ax = fmaf(a, hv.x, ax);
        ay = fmaf(a, hv.y, ay);
        az = fmaf(a, hv.z, az);
        aw = fmaf(a, hv.w, aw);
        asum += a;
    }
    float w = 1.0f / (asum + 1e-16f);
    float4 o = make_float4(ax * w, ay * w, az * w, aw * w);
    ((float4*)outp)[(size_t)node * 32 + lane] = o;
}

// ============================================================
// K5: BN stats: per-channel sum & sumsq over N rows
// ============================================================
__global__ __launch_bounds__(256) void k5_stats(
    const float* __restrict__ outp,
    float* __restrict__ bnsum, float* __restrict__ bnsq)
{
    int c    = threadIdx.x & 127;
    int half = threadIdx.x >> 7;
    int base = blockIdx.x * 128;
    int end  = min(base + 128, N_NODES);
    float sm = 0.f, sq = 0.f;
    for (int r = base + half; r < end; r += 2) {
        float v = outp[(size_t)r * HD + c];
        sm += v;
        sq = fmaf(v, v, sq);
    }
    unsafeAtomicAdd(&bnsum[c], sm);
    unsafeAtomicAdd(&bnsq[c], sq);
}

// ============================================================
// K6: BN apply -> d_out
// ============================================================
__global__ __launch_bounds__(256) void k6_apply(
    const float* __restrict__ outp,
    const float* __restrict__ bnsum, const float* __restrict__ bnsq,
    const float* __restrict__ gamma, const float* __restrict__ beta,
    float* __restrict__ out)
{
    int c    = threadIdx.x & 127;
    int half = threadIdx.x >> 7;
    int base = blockIdx.x * 128;
    int end  = min(base + 128, N_NODES);
    float inv_n = 1.0f / (float)N_NODES;
    float mean = bnsum[c] * inv_n;
    float var  = bnsq[c] * inv_n - mean * mean;
    float scale = gamma[c] * rsqrtf(var + BN_EPS);
    float shift = beta[c] - mean * scale;
    for (int r = base + half; r < end; r += 2) {
        size_t i = (size_t)r * HD + c;
        out[i] = fmaf(outp[i], scale, shift);
    }
}

// ============================================================
extern "C" void kernel_launch(void* const* d_in, const int* in_sizes, int n_in,
                              void* d_out, int out_size, void* d_ws, size_t ws_size,
                              hipStream_t stream)
{
    const float* x     = (const float*)d_in[0];
    const float* W     = (const float*)d_in[1];
    const float* a_src = (const float*)d_in[2];
    const float* a_tgt = (const float*)d_in[3];
    const float* gamma = (const float*)d_in[4];
    const float* beta  = (const float*)d_in[5];
    const int*   eidx  = (const int*)d_in[6];
    const int* src = eidx;
    const int* tgt = eidx + E_EDGES;
    float* out = (float*)d_out;

    // workspace layout (4-byte words)
    float* h      = (float*)d_ws;                       // 6,400,000
    float* s      = h + (size_t)N_NODES * HD;           //   200,000
    float* t      = s + (size_t)N_NODES * HEADS;        //   200,000
    float* outp   = t + (size_t)N_NODES * HEADS;        // 6,400,000
    int*   esrc   = (int*)(outp + (size_t)N_NODES * HD);//   800,000
    int*   rowptr = esrc + E_EDGES;                     //    50,000
    int*   wptr   = rowptr + N_NODES;                   //    50,000
    // ---- zero-init region (single memset) ----
    int*      deg   = wptr + N_NODES;                   //    50,000
    unsigned* smax  = (unsigned*)(deg + N_NODES);       //         4
    unsigned* tmax  = smax + 4;                         //         4
    float*    bnsum = (float*)(tmax + 4);               //       128
    float*    bnsq  = bnsum + HD;                       //       128
    size_t zero_bytes = ((size_t)N_NODES + 8 + HD + HD) * 4;
    hipMemsetAsync(deg, 0, zero_bytes, stream);

    // CSR build
    kc_count<<<(E_EDGES + 255) / 256, 256, 0, stream>>>(tgt, deg);
    kc_scan<<<1, SCAN_T, 0, stream>>>(deg, rowptr, wptr);
    kc_fill<<<(E_EDGES + 255) / 256, 256, 0, stream>>>(src, tgt, wptr, esrc);

    // GEMM + logits
    k1_gemm<<<N_NODES / K1_ROWS, 256, 0, stream>>>(x, W, a_src, a_tgt, h, s, t);
    // per-head node max of s,t (upper bound on edge max; shift cancels)
    k2_nodemax<<<K2_BLOCKS, 256, 0, stream>>>(s, t, smax, tmax);
    // pull aggregation (no atomics)
    long long k4_threads = (long long)N_NODES * 32;
    k4_pull<<<(unsigned)((k4_threads + 255) / 256), 256, 0, stream>>>(
        rowptr, wptr, esrc, s, t, smax, tmax, h, outp);
    // BN
    k5_stats<<<(N_NODES + 127) / 128, 256, 0, stream>>>(outp, bnsum, bnsq);
    k6_apply<<<(N_NODES + 127) / 128, 256, 0, stream>>>(outp, bnsum, bnsq,
                                                        gamma, beta, out);
}

// Round 4
// 431.230 us; speedup vs baseline: 5.4124x; 1.1990x over previous
//
#include <hip/hip_runtime.h>
#include <math.h>

#define N_NODES 50000
#define E_EDGES 800000
#define IN_DIM 128
#define HEADS 4
#define OUT_DIM 32
#define HD 128          // HEADS*OUT_DIM
#define LEAKY 0.4f
#define BN_EPS 1e-5f

typedef __attribute__((ext_vector_type(8))) short short8;
typedef __attribute__((ext_vector_type(4))) float f32x4;

// ---- monotonic float<->uint encoding for atomicMax on floats ----
__device__ __forceinline__ unsigned enc_max(float f) {
    unsigned u = __float_as_uint(f);
    return ((int)u >= 0) ? (u | 0x80000000u) : ~u;
}
__device__ __forceinline__ float dec_max(unsigned u) {
    return (u & 0x80000000u) ? __uint_as_float(u ^ 0x80000000u)
                             : __uint_as_float(~u);
}

__device__ __forceinline__ float leaky(float v) {
    return v > 0.f ? v : LEAKY * v;
}

// fp32 -> bf16 (round-to-nearest-even), finite inputs
__device__ __forceinline__ unsigned short f2bf(float f) {
    unsigned u = __float_as_uint(f);
    u = (u + 0x7FFFu + ((u >> 16) & 1u)) >> 16;
    return (unsigned short)u;
}

// ============================================================
// CSR build: count incoming edges per target
// ============================================================
__global__ __launch_bounds__(256) void kc_count(
    const int* __restrict__ tgt, int* __restrict__ deg)
{
    int e = blockIdx.x * 256 + threadIdx.x;
    if (e < E_EDGES) atomicAdd(&deg[tgt[e]], 1);
}

// ============================================================
// CSR build: single-block exclusive scan of deg -> rowptr (+copy to wptr)
// ============================================================
#define SCAN_T 1024
#define CHUNK ((N_NODES + SCAN_T - 1) / SCAN_T)   // 49
__global__ __launch_bounds__(SCAN_T) void kc_scan(
    const int* __restrict__ deg, int* __restrict__ rowptr, int* __restrict__ wptr)
{
    __shared__ int wsum[SCAN_T / 64];
    int th   = threadIdx.x;
    int beg  = th * CHUNK;
    int end  = min(beg + CHUNK, N_NODES);
    int sum = 0;
    for (int i = beg; i < end; i++) sum += deg[i];

    int lane = th & 63, wid = th >> 6;
    int v = sum;
#pragma unroll
    for (int off = 1; off < 64; off <<= 1) {
        int u = __shfl_up(v, off, 64);
        if (lane >= off) v += u;
    }
    if (lane == 63) wsum[wid] = v;
    __syncthreads();
    int woff = 0;
    for (int w = 0; w < wid; w++) woff += wsum[w];
    int run = woff + (v - sum);       // global exclusive prefix of this chunk
    for (int i = beg; i < end; i++) {
        rowptr[i] = run;
        wptr[i]   = run;
        run += deg[i];
    }
}

// ============================================================
// CSR build: fill source-node list in CSR order (atomic cursor).
// ============================================================
__global__ __launch_bounds__(256) void kc_fill(
    const int* __restrict__ src, const int* __restrict__ tgt,
    int* __restrict__ wptr, int* __restrict__ esrc)
{
    int e = blockIdx.x * 256 + threadIdx.x;
    if (e >= E_EDGES) return;
    int pos = atomicAdd(&wptr[tgt[e]], 1);
    esrc[pos] = src[e];
}

// ============================================================
// K0: cast x to bf16 (RNE)
// ============================================================
#define XQ (N_NODES * IN_DIM / 4)    // 1,600,000 float4 groups
__global__ __launch_bounds__(256) void k_cast(
    const float* __restrict__ x, unsigned short* __restrict__ xbf)
{
    int i = blockIdx.x * 256 + threadIdx.x;
    if (i >= XQ) return;
    float4 v = ((const float4*)x)[i];
    ushort4 o;
    o.x = f2bf(v.x); o.y = f2bf(v.y); o.z = f2bf(v.z); o.w = f2bf(v.w);
    ((ushort4*)xbf)[i] = o;
}

// ============================================================
// K1: h = x @ W via mfma_f32_16x16x32_bf16.
// Block = 4 waves x 16 rows = 64 rows x 128 cols.
// W staged into LDS pre-swizzled into B-fragment layout (32 KB):
//   frag f = nt*4+kc, lane l holds B[k=kc*32+(l>>4)*8+j][col=nt*16+(l&15)]
// A frag: lane l holds A[m=l&15][k=kc*32+(l>>4)*8+j]  (16B contiguous load)
// C/D: col = lane&15, row = (lane>>4)*4 + reg
// ============================================================
__global__ __launch_bounds__(256) void k1_mfma(
    const unsigned short* __restrict__ xbf, const float* __restrict__ W,
    float* __restrict__ h)
{
    __shared__ unsigned short Wl[32 * 64 * 8];   // 32 KB
    const int tid = threadIdx.x;
    for (int idx = tid; idx < 2048; idx += 256) {
        int l  = idx & 63;
        int f  = idx >> 6;
        int nt = f >> 2, kc = f & 3;
        int kbase = kc * 32 + ((l >> 4) << 3);
        int col   = nt * 16 + (l & 15);
        unsigned short* dst = &Wl[idx * 8];
#pragma unroll
        for (int j = 0; j < 8; j++)
            dst[j] = f2bf(W[(kbase + j) * HD + col]);
    }
    __syncthreads();

    const int wave = tid >> 6, lane = tid & 63;
    const int quad = lane >> 4, rl = lane & 15;
    const int row0 = blockIdx.x * 64 + wave * 16;
    const int crow = min(row0 + rl, N_NODES - 1);

    short8 a[4];
    const unsigned short* xp = xbf + (size_t)crow * IN_DIM + quad * 8;
#pragma unroll
    for (int kc = 0; kc < 4; kc++)
        a[kc] = *(const short8*)(xp + kc * 32);

#pragma unroll
    for (int nt = 0; nt < 8; nt++) {
        f32x4 acc = {0.f, 0.f, 0.f, 0.f};
#pragma unroll
        for (int kc = 0; kc < 4; kc++) {
            short8 b = *(const short8*)&Wl[((nt * 4 + kc) * 64 + lane) * 8];
            acc = __builtin_amdgcn_mfma_f32_16x16x32_bf16(a[kc], b, acc, 0, 0, 0);
        }
        int ocol = nt * 16 + rl;
#pragma unroll
        for (int r = 0; r < 4; r++) {
            int orow = row0 + quad * 4 + r;
            if (orow < N_NODES) h[(size_t)orow * HD + ocol] = acc[r];
        }
    }
}

// ============================================================
// K1b: s = h . a_src, t = h . a_tgt  (per node, per head)
// ============================================================
__global__ __launch_bounds__(256) void k_st(
    const float* __restrict__ h, const float* __restrict__ a_src,
    const float* __restrict__ a_tgt, float* __restrict__ s, float* __restrict__ t)
{
    int g = blockIdx.x * 256 + threadIdx.x;   // node*4 + head
    if (g >= N_NODES * HEADS) return;
    int n = g >> 2, hd = g & 3;
    const float4* hp = (const float4*)(h + (size_t)n * HD + hd * OUT_DIM);
    const float4* as = (const float4*)(a_src + hd * OUT_DIM);
    const float4* at = (const float4*)(a_tgt + hd * OUT_DIM);
    float ps = 0.f, pt = 0.f;
#pragma unroll
    for (int j = 0; j < 8; j++) {
        float4 hv = hp[j], av = as[j], bv = at[j];
        ps += hv.x * av.x + hv.y * av.y + hv.z * av.z + hv.w * av.w;
        pt += hv.x * bv.x + hv.y * bv.y + hv.z * bv.z + hv.w * bv.w;
    }
    s[g] = ps; t[g] = pt;
}

// ============================================================
// K2: per-head max over NODES of s and t separately.
// ============================================================
#define K2_BLOCKS 32
__global__ __launch_bounds__(256) void k2_nodemax(
    const float* __restrict__ s, const float* __restrict__ t,
    unsigned* __restrict__ smax, unsigned* __restrict__ tmax)
{
    float sm0 = -INFINITY, sm1 = -INFINITY, sm2 = -INFINITY, sm3 = -INFINITY;
    float tm0 = -INFINITY, tm1 = -INFINITY, tm2 = -INFINITY, tm3 = -INFINITY;
    for (int n = blockIdx.x * 256 + threadIdx.x; n < N_NODES;
         n += K2_BLOCKS * 256) {
        float4 s4 = ((const float4*)s)[n];
        float4 t4 = ((const float4*)t)[n];
        sm0 = fmaxf(sm0, s4.x); sm1 = fmaxf(sm1, s4.y);
        sm2 = fmaxf(sm2, s4.z); sm3 = fmaxf(sm3, s4.w);
        tm0 = fmaxf(tm0, t4.x); tm1 = fmaxf(tm1, t4.y);
        tm2 = fmaxf(tm2, t4.z); tm3 = fmaxf(tm3, t4.w);
    }
#pragma unroll
    for (int m = 32; m >= 1; m >>= 1) {
        sm0 = fmaxf(sm0, __shfl_xor(sm0, m, 64));
        sm1 = fmaxf(sm1, __shfl_xor(sm1, m, 64));
        sm2 = fmaxf(sm2, __shfl_xor(sm2, m, 64));
        sm3 = fmaxf(sm3, __shfl_xor(sm3, m, 64));
        tm0 = fmaxf(tm0, __shfl_xor(tm0, m, 64));
        tm1 = fmaxf(tm1, __shfl_xor(tm1, m, 64));
        tm2 = fmaxf(tm2, __shfl_xor(tm2, m, 64));
        tm3 = fmaxf(tm3, __shfl_xor(tm3, m, 64));
    }
    __shared__ float red[4][8];
    int wid = threadIdx.x >> 6;
    if ((threadIdx.x & 63) == 0) {
        red[wid][0] = sm0; red[wid][1] = sm1; red[wid][2] = sm2; red[wid][3] = sm3;
        red[wid][4] = tm0; red[wid][5] = tm1; red[wid][6] = tm2; red[wid][7] = tm3;
    }
    __syncthreads();
    if (threadIdx.x < 8) {
        float v = fmaxf(fmaxf(red[0][threadIdx.x], red[1][threadIdx.x]),
                        fmaxf(red[2][threadIdx.x], red[3][threadIdx.x]));
        unsigned* dst = (threadIdx.x < 4) ? &smax[threadIdx.x]
                                          : &tmax[threadIdx.x - 4];
        atomicMax(dst, enc_max(v));
    }
}

// ============================================================
// K4: pull aggregation. 32 lanes per target node (float4 each = 128 ch).
// ============================================================
__global__ __launch_bounds__(256) void k4_pull(
    const int* __restrict__ rowptr, const int* __restrict__ wptr,
    const int* __restrict__ esrc,
    const float* __restrict__ s, const float* __restrict__ t,
    const unsigned* __restrict__ smax, const unsigned* __restrict__ tmax,
    const float* __restrict__ h, float* __restrict__ outp)
{
    long long g = (long long)blockIdx.x * 256 + threadIdx.x;
    int node = (int)(g >> 5);
    int lane = (int)(g & 31);
    if (node >= N_NODES) return;
    int head = lane >> 3;
    int beg = rowptr[node];
    int end = wptr[node];          // rowptr[node] + deg[node]
    float mx = leaky(dec_max(smax[head]) + dec_max(tmax[head]));
    float tv = t[node * HEADS + head];

    float ax = 0.f, ay = 0.f, az = 0.f, aw = 0.f, asum = 0.f;
    for (int j = beg; j < end; j++) {
        int si  = esrc[j];
        float sv = s[si * HEADS + head];
        float a  = __expf(leaky(sv + tv) - mx);
        float4 hv = ((const float4*)h)[(size_t)si * 32 + lane];
        ax = fmaf(a, hv.x, ax);
        ay = fmaf(a, hv.y, ay);
        az = fmaf(a, hv.z, az);
        aw = fmaf(a, hv.w, aw);
        asum += a;
    }
    float w = 1.0f / (asum + 1e-16f);
    float4 o = make_float4(ax * w, ay * w, az * w, aw * w);
    ((float4*)outp)[(size_t)node * 32 + lane] = o;
}

// ============================================================
// K5: BN stats: per-channel sum & sumsq over N rows
// ============================================================
__global__ __launch_bounds__(256) void k5_stats(
    const float* __restrict__ outp,
    float* __restrict__ bnsum, float* __restrict__ bnsq)
{
    int c    = threadIdx.x & 127;
    int half = threadIdx.x >> 7;
    int base = blockIdx.x * 128;
    int end  = min(base + 128, N_NODES);
    float sm = 0.f, sq = 0.f;
    for (int r = base + half; r < end; r += 2) {
        float v = outp[(size_t)r * HD + c];
        sm += v;
        sq = fmaf(v, v, sq);
    }
    unsafeAtomicAdd(&bnsum[c], sm);
    unsafeAtomicAdd(&bnsq[c], sq);
}

// ============================================================
// K6: BN apply -> d_out
// ============================================================
__global__ __launch_bounds__(256) void k6_apply(
    const float* __restrict__ outp,
    const float* __restrict__ bnsum, const float* __restrict__ bnsq,
    const float* __restrict__ gamma, const float* __restrict__ beta,
    float* __restrict__ out)
{
    int c    = threadIdx.x & 127;
    int half = threadIdx.x >> 7;
    int base = blockIdx.x * 128;
    int end  = min(base + 128, N_NODES);
    float inv_n = 1.0f / (float)N_NODES;
    float mean = bnsum[c] * inv_n;
    float var  = bnsq[c] * inv_n - mean * mean;
    float scale = gamma[c] * rsqrtf(var + BN_EPS);
    float shift = beta[c] - mean * scale;
    for (int r = base + half; r < end; r += 2) {
        size_t i = (size_t)r * HD + c;
        out[i] = fmaf(outp[i], scale, shift);
    }
}

// ============================================================
extern "C" void kernel_launch(void* const* d_in, const int* in_sizes, int n_in,
                              void* d_out, int out_size, void* d_ws, size_t ws_size,
                              hipStream_t stream)
{
    const float* x     = (const float*)d_in[0];
    const float* W     = (const float*)d_in[1];
    const float* a_src = (const float*)d_in[2];
    const float* a_tgt = (const float*)d_in[3];
    const float* gamma = (const float*)d_in[4];
    const float* beta  = (const float*)d_in[5];
    const int*   eidx  = (const int*)d_in[6];
    const int* src = eidx;
    const int* tgt = eidx + E_EDGES;
    float* out = (float*)d_out;

    // workspace layout (4-byte words)
    float* h      = (float*)d_ws;                       // 6,400,000
    float* s      = h + (size_t)N_NODES * HD;           //   200,000
    float* t      = s + (size_t)N_NODES * HEADS;        //   200,000
    float* outp   = t + (size_t)N_NODES * HEADS;        // 6,400,000
    // xbf aliases outp: k_cast/k1_mfma finish before k4 writes outp
    unsigned short* xbf = (unsigned short*)outp;        // 6,400,000 ushort
    int*   esrc   = (int*)(outp + (size_t)N_NODES * HD);//   800,000
    int*   rowptr = esrc + E_EDGES;                     //    50,000
    int*   wptr   = rowptr + N_NODES;                   //    50,000
    // ---- zero-init region (single memset) ----
    int*      deg   = wptr + N_NODES;                   //    50,000
    unsigned* smax  = (unsigned*)(deg + N_NODES);       //         4
    unsigned* tmax  = smax + 4;                         //         4
    float*    bnsum = (float*)(tmax + 4);               //       128
    float*    bnsq  = bnsum + HD;                       //       128
    size_t zero_bytes = ((size_t)N_NODES + 8 + HD + HD) * 4;
    hipMemsetAsync(deg, 0, zero_bytes, stream);

    // CSR build
    kc_count<<<(E_EDGES + 255) / 256, 256, 0, stream>>>(tgt, deg);
    kc_scan<<<1, SCAN_T, 0, stream>>>(deg, rowptr, wptr);
    kc_fill<<<(E_EDGES + 255) / 256, 256, 0, stream>>>(src, tgt, wptr, esrc);

    // GEMM (bf16 MFMA) + logits
    k_cast<<<(XQ + 255) / 256, 256, 0, stream>>>(x, xbf);
    k1_mfma<<<(N_NODES + 63) / 64, 256, 0, stream>>>(xbf, W, h);
    k_st<<<(N_NODES * HEADS + 255) / 256, 256, 0, stream>>>(h, a_src, a_tgt, s, t);
    // per-head node max of s,t (upper bound on edge max; shift cancels)
    k2_nodemax<<<K2_BLOCKS, 256, 0, stream>>>(s, t, smax, tmax);
    // pull aggregation (no atomics)
    long long k4_threads = (long long)N_NODES * 32;
    k4_pull<<<(unsigned)((k4_threads + 255) / 256), 256, 0, stream>>>(
        rowptr, wptr, esrc, s, t, smax, tmax, h, outp);
    // BN
    k5_stats<<<(N_NODES + 127) / 128, 256, 0, stream>>>(outp, bnsum, bnsq);
    k6_apply<<<(N_NODES + 127) / 128, 256, 0, stream>>>(outp, bnsum, bnsq,
                                                        gamma, beta, out);
}

// Round 5
// 331.324 us; speedup vs baseline: 7.0444x; 1.3015x over previous
//
#include <hip/hip_runtime.h>
#include <math.h>

#define N_NODES 50000
#define E_EDGES 800000
#define IN_DIM 128
#define HEADS 4
#define OUT_DIM 32
#define HD 128          // HEADS*OUT_DIM
#define LEAKY 0.4f
#define BN_EPS 1e-5f

typedef __attribute__((ext_vector_type(8))) short short8;
typedef __attribute__((ext_vector_type(4))) float f32x4;

// ---- monotonic float<->uint encoding for atomicMax on floats ----
__device__ __forceinline__ unsigned enc_max(float f) {
    unsigned u = __float_as_uint(f);
    return ((int)u >= 0) ? (u | 0x80000000u) : ~u;
}
__device__ __forceinline__ float dec_max(unsigned u) {
    return (u & 0x80000000u) ? __uint_as_float(u ^ 0x80000000u)
                             : __uint_as_float(~u);
}

__device__ __forceinline__ float leaky(float v) {
    return v > 0.f ? v : LEAKY * v;
}

// fp32 -> bf16 (round-to-nearest-even), finite inputs
__device__ __forceinline__ unsigned short f2bf(float f) {
    unsigned u = __float_as_uint(f);
    u = (u + 0x7FFFu + ((u >> 16) & 1u)) >> 16;
    return (unsigned short)u;
}

// ============================================================
// CSR build: count incoming edges per target
// ============================================================
__global__ __launch_bounds__(256) void kc_count(
    const int* __restrict__ tgt, int* __restrict__ deg)
{
    int e = blockIdx.x * 256 + threadIdx.x;
    if (e < E_EDGES) atomicAdd(&deg[tgt[e]], 1);
}

// ============================================================
// Device-wide exclusive scan of deg (3 kernels, 256-elem blocks)
// ============================================================
#define SC_T 256
#define SC_B ((N_NODES + SC_T - 1) / SC_T)   // 196

// pass 1: per-block sum
__global__ __launch_bounds__(SC_T) void kc_scan1(
    const int* __restrict__ deg, int* __restrict__ bsum)
{
    int i = blockIdx.x * SC_T + threadIdx.x;
    int v = (i < N_NODES) ? deg[i] : 0;
#pragma unroll
    for (int m = 32; m >= 1; m >>= 1) v += __shfl_xor(v, m, 64);
    __shared__ int ws[4];
    if ((threadIdx.x & 63) == 0) ws[threadIdx.x >> 6] = v;
    __syncthreads();
    if (threadIdx.x == 0) bsum[blockIdx.x] = ws[0] + ws[1] + ws[2] + ws[3];
}

// pass 2: single-block exclusive scan of the 196 block sums
__global__ __launch_bounds__(SC_T) void kc_scan2(
    const int* __restrict__ bsum, int* __restrict__ boff)
{
    int t = threadIdx.x;
    int v = (t < SC_B) ? bsum[t] : 0;
    int lane = t & 63, wid = t >> 6;
    int s = v;
#pragma unroll
    for (int off = 1; off < 64; off <<= 1) {
        int u = __shfl_up(s, off, 64);
        if (lane >= off) s += u;
    }
    __shared__ int ws[4];
    if (lane == 63) ws[wid] = s;
    __syncthreads();
    int add = 0;
    for (int w = 0; w < wid; w++) add += ws[w];
    if (t < SC_B) boff[t] = add + s - v;     // exclusive prefix
}

// pass 3: per-block exclusive scan + block offset -> rowptr, wptr
__global__ __launch_bounds__(SC_T) void kc_scan3(
    const int* __restrict__ deg, const int* __restrict__ boff,
    int* __restrict__ rowptr, int* __restrict__ wptr)
{
    int i = blockIdx.x * SC_T + threadIdx.x;
    int v = (i < N_NODES) ? deg[i] : 0;
    int lane = threadIdx.x & 63, wid = threadIdx.x >> 6;
    int s = v;
#pragma unroll
    for (int off = 1; off < 64; off <<= 1) {
        int u = __shfl_up(s, off, 64);
        if (lane >= off) s += u;
    }
    __shared__ int ws[4];
    if (lane == 63) ws[wid] = s;
    __syncthreads();
    int add = boff[blockIdx.x];
    for (int w = 0; w < wid; w++) add += ws[w];
    int ex = add + s - v;
    if (i < N_NODES) { rowptr[i] = ex; wptr[i] = ex; }
}

// ============================================================
// CSR build: fill source-node list in CSR order (atomic cursor).
// ============================================================
__global__ __launch_bounds__(256) void kc_fill(
    const int* __restrict__ src, const int* __restrict__ tgt,
    int* __restrict__ wptr, int* __restrict__ esrc)
{
    int e = blockIdx.x * 256 + threadIdx.x;
    if (e >= E_EDGES) return;
    int pos = atomicAdd(&wptr[tgt[e]], 1);
    esrc[pos] = src[e];
}

// ============================================================
// K0: cast x to bf16 (RNE)
// ============================================================
#define XQ (N_NODES * IN_DIM / 4)    // 1,600,000 float4 groups
__global__ __launch_bounds__(256) void k_cast(
    const float* __restrict__ x, unsigned short* __restrict__ xbf)
{
    int i = blockIdx.x * 256 + threadIdx.x;
    if (i >= XQ) return;
    float4 v = ((const float4*)x)[i];
    ushort4 o;
    o.x = f2bf(v.x); o.y = f2bf(v.y); o.z = f2bf(v.z); o.w = f2bf(v.w);
    ((ushort4*)xbf)[i] = o;
}

// ============================================================
// K1: h = x @ W via mfma_f32_16x16x32_bf16.
// Block = 4 waves x 16 rows = 64 rows x 128 cols.
// W staged into LDS pre-swizzled into B-fragment layout (32 KB).
// ============================================================
__global__ __launch_bounds__(256) void k1_mfma(
    const unsigned short* __restrict__ xbf, const float* __restrict__ W,
    float* __restrict__ h)
{
    __shared__ unsigned short Wl[32 * 64 * 8];   // 32 KB
    const int tid = threadIdx.x;
    for (int idx = tid; idx < 2048; idx += 256) {
        int l  = idx & 63;
        int f  = idx >> 6;
        int nt = f >> 2, kc = f & 3;
        int kbase = kc * 32 + ((l >> 4) << 3);
        int col   = nt * 16 + (l & 15);
        unsigned short* dst = &Wl[idx * 8];
#pragma unroll
        for (int j = 0; j < 8; j++)
            dst[j] = f2bf(W[(kbase + j) * HD + col]);
    }
    __syncthreads();

    const int wave = tid >> 6, lane = tid & 63;
    const int quad = lane >> 4, rl = lane & 15;
    const int row0 = blockIdx.x * 64 + wave * 16;
    const int crow = min(row0 + rl, N_NODES - 1);

    short8 a[4];
    const unsigned short* xp = xbf + (size_t)crow * IN_DIM + quad * 8;
#pragma unroll
    for (int kc = 0; kc < 4; kc++)
        a[kc] = *(const short8*)(xp + kc * 32);

#pragma unroll
    for (int nt = 0; nt < 8; nt++) {
        f32x4 acc = {0.f, 0.f, 0.f, 0.f};
#pragma unroll
        for (int kc = 0; kc < 4; kc++) {
            short8 b = *(const short8*)&Wl[((nt * 4 + kc) * 64 + lane) * 8];
            acc = __builtin_amdgcn_mfma_f32_16x16x32_bf16(a[kc], b, acc, 0, 0, 0);
        }
        int ocol = nt * 16 + rl;
#pragma unroll
        for (int r = 0; r < 4; r++) {
            int orow = row0 + quad * 4 + r;
            if (orow < N_NODES) h[(size_t)orow * HD + ocol] = acc[r];
        }
    }
}

// ============================================================
// K1b: s = h . a_src, t = h . a_tgt  (per node, per head)
// ============================================================
__global__ __launch_bounds__(256) void k_st(
    const float* __restrict__ h, const float* __restrict__ a_src,
    const float* __restrict__ a_tgt, float* __restrict__ s, float* __restrict__ t)
{
    int g = blockIdx.x * 256 + threadIdx.x;   // node*4 + head
    if (g >= N_NODES * HEADS) return;
    int n = g >> 2, hd = g & 3;
    const float4* hp = (const float4*)(h + (size_t)n * HD + hd * OUT_DIM);
    const float4* as = (const float4*)(a_src + hd * OUT_DIM);
    const float4* at = (const float4*)(a_tgt + hd * OUT_DIM);
    float ps = 0.f, pt = 0.f;
#pragma unroll
    for (int j = 0; j < 8; j++) {
        float4 hv = hp[j], av = as[j], bv = at[j];
        ps += hv.x * av.x + hv.y * av.y + hv.z * av.z + hv.w * av.w;
        pt += hv.x * bv.x + hv.y * bv.y + hv.z * bv.z + hv.w * bv.w;
    }
    s[g] = ps; t[g] = pt;
}

// ============================================================
// K2: per-head max over NODES of s and t separately.
// ============================================================
#define K2_BLOCKS 32
__global__ __launch_bounds__(256) void k2_nodemax(
    const float* __restrict__ s, const float* __restrict__ t,
    unsigned* __restrict__ smax, unsigned* __restrict__ tmax)
{
    float sm0 = -INFINITY, sm1 = -INFINITY, sm2 = -INFINITY, sm3 = -INFINITY;
    float tm0 = -INFINITY, tm1 = -INFINITY, tm2 = -INFINITY, tm3 = -INFINITY;
    for (int n = blockIdx.x * 256 + threadIdx.x; n < N_NODES;
         n += K2_BLOCKS * 256) {
        float4 s4 = ((const float4*)s)[n];
        float4 t4 = ((const float4*)t)[n];
        sm0 = fmaxf(sm0, s4.x); sm1 = fmaxf(sm1, s4.y);
        sm2 = fmaxf(sm2, s4.z); sm3 = fmaxf(sm3, s4.w);
        tm0 = fmaxf(tm0, t4.x); tm1 = fmaxf(tm1, t4.y);
        tm2 = fmaxf(tm2, t4.z); tm3 = fmaxf(tm3, t4.w);
    }
#pragma unroll
    for (int m = 32; m >= 1; m >>= 1) {
        sm0 = fmaxf(sm0, __shfl_xor(sm0, m, 64));
        sm1 = fmaxf(sm1, __shfl_xor(sm1, m, 64));
        sm2 = fmaxf(sm2, __shfl_xor(sm2, m, 64));
        sm3 = fmaxf(sm3, __shfl_xor(sm3, m, 64));
        tm0 = fmaxf(tm0, __shfl_xor(tm0, m, 64));
        tm1 = fmaxf(tm1, __shfl_xor(tm1, m, 64));
        tm2 = fmaxf(tm2, __shfl_xor(tm2, m, 64));
        tm3 = fmaxf(tm3, __shfl_xor(tm3, m, 64));
    }
    __shared__ float red[4][8];
    int wid = threadIdx.x >> 6;
    if ((threadIdx.x & 63) == 0) {
        red[wid][0] = sm0; red[wid][1] = sm1; red[wid][2] = sm2; red[wid][3] = sm3;
        red[wid][4] = tm0; red[wid][5] = tm1; red[wid][6] = tm2; red[wid][7] = tm3;
    }
    __syncthreads();
    if (threadIdx.x < 8) {
        float v = fmaxf(fmaxf(red[0][threadIdx.x], red[1][threadIdx.x]),
                        fmaxf(red[2][threadIdx.x], red[3][threadIdx.x]));
        unsigned* dst = (threadIdx.x < 4) ? &smax[threadIdx.x]
                                          : &tmax[threadIdx.x - 4];
        atomicMax(dst, enc_max(v));
    }
}

// ============================================================
// K4: pull aggregation. 32 lanes per target node (float4 each = 128 ch).
// ============================================================
__global__ __launch_bounds__(256) void k4_pull(
    const int* __restrict__ rowptr, const int* __restrict__ wptr,
    const int* __restrict__ esrc,
    const float* __restrict__ s, const float* __restrict__ t,
    const unsigned* __restrict__ smax, const unsigned* __restrict__ tmax,
    const float* __restrict__ h, float* __restrict__ outp)
{
    long long g = (long long)blockIdx.x * 256 + threadIdx.x;
    int node = (int)(g >> 5);
    int lane = (int)(g & 31);
    if (node >= N_NODES) return;
    int head = lane >> 3;
    int beg = rowptr[node];
    int end = wptr[node];          // rowptr[node] + deg[node]
    float mx = leaky(dec_max(smax[head]) + dec_max(tmax[head]));
    float tv = t[node * HEADS + head];

    float ax = 0.f, ay = 0.f, az = 0.f, aw = 0.f, asum = 0.f;
    for (int j = beg; j < end; j++) {
        int si  = esrc[j];
        float sv = s[si * HEADS + head];
        float a  = __expf(leaky(sv + tv) - mx);
        float4 hv = ((const float4*)h)[(size_t)si * 32 + lane];
        ax = fmaf(a, hv.x, ax);
        ay = fmaf(a, hv.y, ay);
        az = fmaf(a, hv.z, az);
        aw = fmaf(a, hv.w, aw);
        asum += a;
    }
    float w = 1.0f / (asum + 1e-16f);
    float4 o = make_float4(ax * w, ay * w, az * w, aw * w);
    ((float4*)outp)[(size_t)node * 32 + lane] = o;
}

// ============================================================
// K5: BN stats: per-channel sum & sumsq over N rows
// ============================================================
__global__ __launch_bounds__(256) void k5_stats(
    const float* __restrict__ outp,
    float* __restrict__ bnsum, float* __restrict__ bnsq)
{
    int c    = threadIdx.x & 127;
    int half = threadIdx.x >> 7;
    int base = blockIdx.x * 128;
    int end  = min(base + 128, N_NODES);
    float sm = 0.f, sq = 0.f;
    for (int r = base + half; r < end; r += 2) {
        float v = outp[(size_t)r * HD + c];
        sm += v;
        sq = fmaf(v, v, sq);
    }
    unsafeAtomicAdd(&bnsum[c], sm);
    unsafeAtomicAdd(&bnsq[c], sq);
}

// ============================================================
// K6: BN apply -> d_out
// ============================================================
__global__ __launch_bounds__(256) void k6_apply(
    const float* __restrict__ outp,
    const float* __restrict__ bnsum, const float* __restrict__ bnsq,
    const float* __restrict__ gamma, const float* __restrict__ beta,
    float* __restrict__ out)
{
    int c    = threadIdx.x & 127;
    int half = threadIdx.x >> 7;
    int base = blockIdx.x * 128;
    int end  = min(base + 128, N_NODES);
    float inv_n = 1.0f / (float)N_NODES;
    float mean = bnsum[c] * inv_n;
    float var  = bnsq[c] * inv_n - mean * mean;
    float scale = gamma[c] * rsqrtf(var + BN_EPS);
    float shift = beta[c] - mean * scale;
    for (int r = base + half; r < end; r += 2) {
        size_t i = (size_t)r * HD + c;
        out[i] = fmaf(outp[i], scale, shift);
    }
}

// ============================================================
extern "C" void kernel_launch(void* const* d_in, const int* in_sizes, int n_in,
                              void* d_out, int out_size, void* d_ws, size_t ws_size,
                              hipStream_t stream)
{
    const float* x     = (const float*)d_in[0];
    const float* W     = (const float*)d_in[1];
    const float* a_src = (const float*)d_in[2];
    const float* a_tgt = (const float*)d_in[3];
    const float* gamma = (const float*)d_in[4];
    const float* beta  = (const float*)d_in[5];
    const int*   eidx  = (const int*)d_in[6];
    const int* src = eidx;
    const int* tgt = eidx + E_EDGES;
    float* out = (float*)d_out;

    // workspace layout (4-byte words)
    float* h      = (float*)d_ws;                       // 6,400,000
    float* s      = h + (size_t)N_NODES * HD;           //   200,000
    float* t      = s + (size_t)N_NODES * HEADS;        //   200,000
    float* outp   = t + (size_t)N_NODES * HEADS;        // 6,400,000
    // xbf aliases outp: k_cast/k1_mfma finish before k4 writes outp
    unsigned short* xbf = (unsigned short*)outp;        // 6,400,000 ushort
    int*   esrc   = (int*)(outp + (size_t)N_NODES * HD);//   800,000
    int*   rowptr = esrc + E_EDGES;                     //    50,000
    int*   wptr   = rowptr + N_NODES;                   //    50,000
    int*   bsum   = wptr + N_NODES;                     //       256
    int*   boff   = bsum + 256;                         //       256
    // ---- zero-init region (single memset) ----
    int*      deg   = boff + 256;                       //    50,000
    unsigned* smax  = (unsigned*)(deg + N_NODES);       //         4
    unsigned* tmax  = smax + 4;                         //         4
    float*    bnsum = (float*)(tmax + 4);               //       128
    float*    bnsq  = bnsum + HD;                       //       128
    size_t zero_bytes = ((size_t)N_NODES + 8 + HD + HD) * 4;
    hipMemsetAsync(deg, 0, zero_bytes, stream);

    // CSR build
    kc_count<<<(E_EDGES + 255) / 256, 256, 0, stream>>>(tgt, deg);
    kc_scan1<<<SC_B, SC_T, 0, stream>>>(deg, bsum);
    kc_scan2<<<1, SC_T, 0, stream>>>(bsum, boff);
    kc_scan3<<<SC_B, SC_T, 0, stream>>>(deg, boff, rowptr, wptr);
    kc_fill<<<(E_EDGES + 255) / 256, 256, 0, stream>>>(src, tgt, wptr, esrc);

    // GEMM (bf16 MFMA) + logits
    k_cast<<<(XQ + 255) / 256, 256, 0, stream>>>(x, xbf);
    k1_mfma<<<(N_NODES + 63) / 64, 256, 0, stream>>>(xbf, W, h);
    k_st<<<(N_NODES * HEADS + 255) / 256, 256, 0, stream>>>(h, a_src, a_tgt, s, t);
    // per-head node max of s,t (upper bound on edge max; shift cancels)
    k2_nodemax<<<K2_BLOCKS, 256, 0, stream>>>(s, t, smax, tmax);
    // pull aggregation (no atomics)
    long long k4_threads = (long long)N_NODES * 32;
    k4_pull<<<(unsigned)((k4_threads + 255) / 256), 256, 0, stream>>>(
        rowptr, wptr, esrc, s, t, smax, tmax, h, outp);
    // BN
    k5_stats<<<(N_NODES + 127) / 128, 256, 0, stream>>>(outp, bnsum, bnsq);
    k6_apply<<<(N_NODES + 127) / 128, 256, 0, stream>>>(outp, bnsum, bnsq,
                                                        gamma, beta, out);
}

// Round 6
// 287.204 us; speedup vs baseline: 8.1265x; 1.1536x over previous
//
#include <hip/hip_runtime.h>
#include <math.h>

#define N_NODES 50000
#define E_EDGES 800000
#define IN_DIM 128
#define HEADS 4
#define OUT_DIM 32
#define HD 128          // HEADS*OUT_DIM
#define LEAKY 0.4f
#define BN_EPS 1e-5f

typedef __attribute__((ext_vector_type(8))) short short8;
typedef __attribute__((ext_vector_type(8))) unsigned short us8;
typedef __attribute__((ext_vector_type(4))) float f32x4;

// ---- monotonic float<->uint encoding for atomicMax on floats ----
__device__ __forceinline__ unsigned enc_max(float f) {
    unsigned u = __float_as_uint(f);
    return ((int)u >= 0) ? (u | 0x80000000u) : ~u;
}
__device__ __forceinline__ float dec_max(unsigned u) {
    return (u & 0x80000000u) ? __uint_as_float(u ^ 0x80000000u)
                             : __uint_as_float(~u);
}

__device__ __forceinline__ float leaky(float v) {
    return v > 0.f ? v : LEAKY * v;
}

// fp32 -> bf16 (round-to-nearest-even), finite inputs
__device__ __forceinline__ unsigned short f2bf(float f) {
    unsigned u = __float_as_uint(f);
    u = (u + 0x7FFFu + ((u >> 16) & 1u)) >> 16;
    return (unsigned short)u;
}
__device__ __forceinline__ float bf2f(unsigned short u) {
    return __uint_as_float(((unsigned)u) << 16);
}

// ============================================================
// CSR build: count incoming edges per target
// ============================================================
__global__ __launch_bounds__(256) void kc_count(
    const int* __restrict__ tgt, int* __restrict__ deg)
{
    int e = blockIdx.x * 256 + threadIdx.x;
    if (e < E_EDGES) atomicAdd(&deg[tgt[e]], 1);
}

// ============================================================
// Device-wide exclusive scan of deg (3 kernels, 256-elem blocks)
// ============================================================
#define SC_T 256
#define SC_B ((N_NODES + SC_T - 1) / SC_T)   // 196

__global__ __launch_bounds__(SC_T) void kc_scan1(
    const int* __restrict__ deg, int* __restrict__ bsum)
{
    int i = blockIdx.x * SC_T + threadIdx.x;
    int v = (i < N_NODES) ? deg[i] : 0;
#pragma unroll
    for (int m = 32; m >= 1; m >>= 1) v += __shfl_xor(v, m, 64);
    __shared__ int ws[4];
    if ((threadIdx.x & 63) == 0) ws[threadIdx.x >> 6] = v;
    __syncthreads();
    if (threadIdx.x == 0) bsum[blockIdx.x] = ws[0] + ws[1] + ws[2] + ws[3];
}

__global__ __launch_bounds__(SC_T) void kc_scan2(
    const int* __restrict__ bsum, int* __restrict__ boff)
{
    int t = threadIdx.x;
    int v = (t < SC_B) ? bsum[t] : 0;
    int lane = t & 63, wid = t >> 6;
    int s = v;
#pragma unroll
    for (int off = 1; off < 64; off <<= 1) {
        int u = __shfl_up(s, off, 64);
        if (lane >= off) s += u;
    }
    __shared__ int ws[4];
    if (lane == 63) ws[wid] = s;
    __syncthreads();
    int add = 0;
    for (int w = 0; w < wid; w++) add += ws[w];
    if (t < SC_B) boff[t] = add + s - v;     // exclusive prefix
}

__global__ __launch_bounds__(SC_T) void kc_scan3(
    const int* __restrict__ deg, const int* __restrict__ boff,
    int* __restrict__ rowptr, int* __restrict__ wptr)
{
    int i = blockIdx.x * SC_T + threadIdx.x;
    int v = (i < N_NODES) ? deg[i] : 0;
    int lane = threadIdx.x & 63, wid = threadIdx.x >> 6;
    int s = v;
#pragma unroll
    for (int off = 1; off < 64; off <<= 1) {
        int u = __shfl_up(s, off, 64);
        if (lane >= off) s += u;
    }
    __shared__ int ws[4];
    if (lane == 63) ws[wid] = s;
    __syncthreads();
    int add = boff[blockIdx.x];
    for (int w = 0; w < wid; w++) add += ws[w];
    int ex = add + s - v;
    if (i < N_NODES) { rowptr[i] = ex; wptr[i] = ex; }
}

// ============================================================
// CSR build: fill source-node list in CSR order (atomic cursor).
// ============================================================
__global__ __launch_bounds__(256) void kc_fill(
    const int* __restrict__ src, const int* __restrict__ tgt,
    int* __restrict__ wptr, int* __restrict__ esrc)
{
    int e = blockIdx.x * 256 + threadIdx.x;
    if (e >= E_EDGES) return;
    int pos = atomicAdd(&wptr[tgt[e]], 1);
    esrc[pos] = src[e];
}

// ============================================================
// K1: h = x @ W via mfma_f32_16x16x32_bf16, fp32 x converted inline.
// Block = 4 waves x 16 rows = 64 rows x 128 cols.
// W staged into LDS pre-swizzled into B-fragment layout (32 KB).
// Epilogue: h stored as bf16 (hb); s/t logit dots fused via 16-lane
// xor-shuffle reduction (C/D layout: col = lane&15, row = quad*4+reg).
// ============================================================
__global__ __launch_bounds__(256) void k1_mfma(
    const float* __restrict__ x, const float* __restrict__ W,
    const float* __restrict__ a_src, const float* __restrict__ a_tgt,
    unsigned short* __restrict__ hb, float* __restrict__ s,
    float* __restrict__ t)
{
    __shared__ unsigned short Wl[32 * 64 * 8];   // 32 KB
    const int tid = threadIdx.x;
    for (int idx = tid; idx < 2048; idx += 256) {
        int l  = idx & 63;
        int f  = idx >> 6;
        int nt = f >> 2, kc = f & 3;
        int kbase = kc * 32 + ((l >> 4) << 3);
        int col   = nt * 16 + (l & 15);
        unsigned short* dst = &Wl[idx * 8];
#pragma unroll
        for (int j = 0; j < 8; j++)
            dst[j] = f2bf(W[(kbase + j) * HD + col]);
    }
    __syncthreads();

    const int wave = tid >> 6, lane = tid & 63;
    const int quad = lane >> 4, rl = lane & 15;
    const int row0 = blockIdx.x * 64 + wave * 16;
    const int crow = min(row0 + rl, N_NODES - 1);

    // A fragments: 8 consecutive fp32 -> bf16x8 per kc
    short8 a[4];
    const float* xp = x + (size_t)crow * IN_DIM + quad * 8;
#pragma unroll
    for (int kc = 0; kc < 4; kc++) {
        float4 v0 = *(const float4*)(xp + kc * 32);
        float4 v1 = *(const float4*)(xp + kc * 32 + 4);
        short8 av;
        av[0] = (short)f2bf(v0.x); av[1] = (short)f2bf(v0.y);
        av[2] = (short)f2bf(v0.z); av[3] = (short)f2bf(v0.w);
        av[4] = (short)f2bf(v1.x); av[5] = (short)f2bf(v1.y);
        av[6] = (short)f2bf(v1.z); av[7] = (short)f2bf(v1.w);
        a[kc] = av;
    }

    // attention vector elements for this lane's columns
    float asv[8], atv[8];
#pragma unroll
    for (int nt = 0; nt < 8; nt++) {
        asv[nt] = a_src[nt * 16 + rl];
        atv[nt] = a_tgt[nt * 16 + rl];
    }

    float ps[4][4], pt[4][4];   // [head][r]
#pragma unroll
    for (int hh = 0; hh < 4; hh++)
#pragma unroll
        for (int r = 0; r < 4; r++) { ps[hh][r] = 0.f; pt[hh][r] = 0.f; }

#pragma unroll
    for (int nt = 0; nt < 8; nt++) {
        f32x4 acc = {0.f, 0.f, 0.f, 0.f};
#pragma unroll
        for (int kc = 0; kc < 4; kc++) {
            short8 b = *(const short8*)&Wl[((nt * 4 + kc) * 64 + lane) * 8];
            acc = __builtin_amdgcn_mfma_f32_16x16x32_bf16(a[kc], b, acc, 0, 0, 0);
        }
        const int ocol = nt * 16 + rl;
        const int hh   = nt >> 1;
#pragma unroll
        for (int r = 0; r < 4; r++) {
            int orow = row0 + quad * 4 + r;
            if (orow < N_NODES)
                hb[(size_t)orow * HD + ocol] = f2bf(acc[r]);
            ps[hh][r] = fmaf(acc[r], asv[nt], ps[hh][r]);
            pt[hh][r] = fmaf(acc[r], atv[nt], pt[hh][r]);
        }
    }

    // reduce ps/pt across the 16 rl-lanes (masks stay within quad)
#pragma unroll
    for (int m = 1; m <= 8; m <<= 1) {
#pragma unroll
        for (int hh = 0; hh < 4; hh++)
#pragma unroll
            for (int r = 0; r < 4; r++) {
                ps[hh][r] += __shfl_xor(ps[hh][r], m, 64);
                pt[hh][r] += __shfl_xor(pt[hh][r], m, 64);
            }
    }
    if (rl == 0) {
#pragma unroll
        for (int r = 0; r < 4; r++) {
            int orow = row0 + quad * 4 + r;
            if (orow < N_NODES) {
#pragma unroll
                for (int hh = 0; hh < 4; hh++) {
                    s[orow * HEADS + hh] = ps[hh][r];
                    t[orow * HEADS + hh] = pt[hh][r];
                }
            }
        }
    }
}

// ============================================================
// K2: per-head max over NODES of s and t separately.
// ============================================================
#define K2_BLOCKS 32
__global__ __launch_bounds__(256) void k2_nodemax(
    const float* __restrict__ s, const float* __restrict__ t,
    unsigned* __restrict__ smax, unsigned* __restrict__ tmax)
{
    float sm0 = -INFINITY, sm1 = -INFINITY, sm2 = -INFINITY, sm3 = -INFINITY;
    float tm0 = -INFINITY, tm1 = -INFINITY, tm2 = -INFINITY, tm3 = -INFINITY;
    for (int n = blockIdx.x * 256 + threadIdx.x; n < N_NODES;
         n += K2_BLOCKS * 256) {
        float4 s4 = ((const float4*)s)[n];
        float4 t4 = ((const float4*)t)[n];
        sm0 = fmaxf(sm0, s4.x); sm1 = fmaxf(sm1, s4.y);
        sm2 = fmaxf(sm2, s4.z); sm3 = fmaxf(sm3, s4.w);
        tm0 = fmaxf(tm0, t4.x); tm1 = fmaxf(tm1, t4.y);
        tm2 = fmaxf(tm2, t4.z); tm3 = fmaxf(tm3, t4.w);
    }
#pragma unroll
    for (int m = 32; m >= 1; m >>= 1) {
        sm0 = fmaxf(sm0, __shfl_xor(sm0, m, 64));
        sm1 = fmaxf(sm1, __shfl_xor(sm1, m, 64));
        sm2 = fmaxf(sm2, __shfl_xor(sm2, m, 64));
        sm3 = fmaxf(sm3, __shfl_xor(sm3, m, 64));
        tm0 = fmaxf(tm0, __shfl_xor(tm0, m, 64));
        tm1 = fmaxf(tm1, __shfl_xor(tm1, m, 64));
        tm2 = fmaxf(tm2, __shfl_xor(tm2, m, 64));
        tm3 = fmaxf(tm3, __shfl_xor(tm3, m, 64));
    }
    __shared__ float red[4][8];
    int wid = threadIdx.x >> 6;
    if ((threadIdx.x & 63) == 0) {
        red[wid][0] = sm0; red[wid][1] = sm1; red[wid][2] = sm2; red[wid][3] = sm3;
        red[wid][4] = tm0; red[wid][5] = tm1; red[wid][6] = tm2; red[wid][7] = tm3;
    }
    __syncthreads();
    if (threadIdx.x < 8) {
        float v = fmaxf(fmaxf(red[0][threadIdx.x], red[1][threadIdx.x]),
                        fmaxf(red[2][threadIdx.x], red[3][threadIdx.x]));
        unsigned* dst = (threadIdx.x < 4) ? &smax[threadIdx.x]
                                          : &tmax[threadIdx.x - 4];
        atomicMax(dst, enc_max(v));
    }
}

// ============================================================
// K4: pull aggregation. 16 lanes per target node, 8 bf16 ch each (16 B).
// ============================================================
__global__ __launch_bounds__(256) void k4_pull(
    const int* __restrict__ rowptr, const int* __restrict__ wptr,
    const int* __restrict__ esrc,
    const float* __restrict__ s, const float* __restrict__ t,
    const unsigned* __restrict__ smax, const unsigned* __restrict__ tmax,
    const unsigned short* __restrict__ hb, float* __restrict__ outp)
{
    int g = blockIdx.x * 256 + threadIdx.x;
    int node = g >> 4;
    int lane = g & 15;
    if (node >= N_NODES) return;
    int head = lane >> 2;                 // 4 lanes per head, 8 ch each
    int beg = rowptr[node];
    int end = wptr[node];                 // rowptr[node] + deg[node]
    float mx = leaky(dec_max(smax[head]) + dec_max(tmax[head]));
    float tv = t[node * HEADS + head];

    float a0 = 0.f, a1 = 0.f, a2 = 0.f, a3 = 0.f;
    float a4 = 0.f, a5 = 0.f, a6 = 0.f, a7 = 0.f, asum = 0.f;
    const unsigned short* hbase = hb + lane * 8;
    for (int j = beg; j < end; j++) {
        int si  = esrc[j];
        float sv = s[si * HEADS + head];
        float a  = __expf(leaky(sv + tv) - mx);
        us8 hv = *(const us8*)(hbase + (size_t)si * HD);
        a0 = fmaf(a, bf2f(hv[0]), a0);
        a1 = fmaf(a, bf2f(hv[1]), a1);
        a2 = fmaf(a, bf2f(hv[2]), a2);
        a3 = fmaf(a, bf2f(hv[3]), a3);
        a4 = fmaf(a, bf2f(hv[4]), a4);
        a5 = fmaf(a, bf2f(hv[5]), a5);
        a6 = fmaf(a, bf2f(hv[6]), a6);
        a7 = fmaf(a, bf2f(hv[7]), a7);
        asum += a;
    }
    float w = 1.0f / (asum + 1e-16f);
    float4* op = (float4*)(outp + (size_t)node * HD + lane * 8);
    op[0] = make_float4(a0 * w, a1 * w, a2 * w, a3 * w);
    op[1] = make_float4(a4 * w, a5 * w, a6 * w, a7 * w);
}

// ============================================================
// K5: BN stats: per-channel sum & sumsq over N rows
// ============================================================
__global__ __launch_bounds__(256) void k5_stats(
    const float* __restrict__ outp,
    float* __restrict__ bnsum, float* __restrict__ bnsq)
{
    int c    = threadIdx.x & 127;
    int half = threadIdx.x >> 7;
    int base = blockIdx.x * 128;
    int end  = min(base + 128, N_NODES);
    float sm = 0.f, sq = 0.f;
    for (int r = base + half; r < end; r += 2) {
        float v = outp[(size_t)r * HD + c];
        sm += v;
        sq = fmaf(v, v, sq);
    }
    unsafeAtomicAdd(&bnsum[c], sm);
    unsafeAtomicAdd(&bnsq[c], sq);
}

// ============================================================
// K6: BN apply -> d_out
// ============================================================
__global__ __launch_bounds__(256) void k6_apply(
    const float* __restrict__ outp,
    const float* __restrict__ bnsum, const float* __restrict__ bnsq,
    const float* __restrict__ gamma, const float* __restrict__ beta,
    float* __restrict__ out)
{
    int c    = threadIdx.x & 127;
    int half = threadIdx.x >> 7;
    int base = blockIdx.x * 128;
    int end  = min(base + 128, N_NODES);
    float inv_n = 1.0f / (float)N_NODES;
    float mean = bnsum[c] * inv_n;
    float var  = bnsq[c] * inv_n - mean * mean;
    float scale = gamma[c] * rsqrtf(var + BN_EPS);
    float shift = beta[c] - mean * scale;
    for (int r = base + half; r < end; r += 2) {
        size_t i = (size_t)r * HD + c;
        out[i] = fmaf(outp[i], scale, shift);
    }
}

// ============================================================
extern "C" void kernel_launch(void* const* d_in, const int* in_sizes, int n_in,
                              void* d_out, int out_size, void* d_ws, size_t ws_size,
                              hipStream_t stream)
{
    const float* x     = (const float*)d_in[0];
    const float* W     = (const float*)d_in[1];
    const float* a_src = (const float*)d_in[2];
    const float* a_tgt = (const float*)d_in[3];
    const float* gamma = (const float*)d_in[4];
    const float* beta  = (const float*)d_in[5];
    const int*   eidx  = (const int*)d_in[6];
    const int* src = eidx;
    const int* tgt = eidx + E_EDGES;
    float* out = (float*)d_out;

    // workspace layout (4-byte words)
    unsigned short* hb = (unsigned short*)d_ws;         // 6,400,000 ushort
    float* s      = (float*)d_ws + 3200000;             //   200,000
    float* t      = s + (size_t)N_NODES * HEADS;        //   200,000
    float* outp   = t + (size_t)N_NODES * HEADS;        // 6,400,000
    int*   esrc   = (int*)(outp + (size_t)N_NODES * HD);//   800,000
    int*   rowptr = esrc + E_EDGES;                     //    50,000
    int*   wptr   = rowptr + N_NODES;                   //    50,000
    int*   bsum   = wptr + N_NODES;                     //       256
    int*   boff   = bsum + 256;                         //       256
    // ---- zero-init region (single memset) ----
    int*      deg   = boff + 256;                       //    50,000
    unsigned* smax  = (unsigned*)(deg + N_NODES);       //         4
    unsigned* tmax  = smax + 4;                         //         4
    float*    bnsum = (float*)(tmax + 4);               //       128
    float*    bnsq  = bnsum + HD;                       //       128
    size_t zero_bytes = ((size_t)N_NODES + 8 + HD + HD) * 4;
    hipMemsetAsync(deg, 0, zero_bytes, stream);

    // CSR build
    kc_count<<<(E_EDGES + 255) / 256, 256, 0, stream>>>(tgt, deg);
    kc_scan1<<<SC_B, SC_T, 0, stream>>>(deg, bsum);
    kc_scan2<<<1, SC_T, 0, stream>>>(bsum, boff);
    kc_scan3<<<SC_B, SC_T, 0, stream>>>(deg, boff, rowptr, wptr);
    kc_fill<<<(E_EDGES + 255) / 256, 256, 0, stream>>>(src, tgt, wptr, esrc);

    // GEMM (bf16 MFMA) with fused bf16-h store + s/t logits
    k1_mfma<<<(N_NODES + 63) / 64, 256, 0, stream>>>(x, W, a_src, a_tgt,
                                                     hb, s, t);
    // per-head node max of s,t (upper bound on edge max; shift cancels)
    k2_nodemax<<<K2_BLOCKS, 256, 0, stream>>>(s, t, smax, tmax);
    // pull aggregation (no atomics), bf16 h gather
    long long k4_threads = (long long)N_NODES * 16;
    k4_pull<<<(unsigned)((k4_threads + 255) / 256), 256, 0, stream>>>(
        rowptr, wptr, esrc, s, t, smax, tmax, hb, outp);
    // BN
    k5_stats<<<(N_NODES + 127) / 128, 256, 0, stream>>>(outp, bnsum, bnsq);
    k6_apply<<<(N_NODES + 127) / 128, 256, 0, stream>>>(outp, bnsum, bnsq,
                                                        gamma, beta, out);
}

// Round 7
// 245.489 us; speedup vs baseline: 9.5075x; 1.1699x over previous
//
#include <hip/hip_runtime.h>
#include <math.h>

#define N_NODES 50000
#define E_EDGES 800000
#define IN_DIM 128
#define HEADS 4
#define OUT_DIM 32
#define HD 128          // HEADS*OUT_DIM
#define LEAKY 0.4f
#define BN_EPS 1e-5f

// bucketed counting sort params: bucket = tgt >> 7 (128 targets/bucket)
#define BSH 7
#define NB ((N_NODES + 127) >> BSH)     // 391
#define FB 196                           // kb_fill blocks
#define FCH 4096                         // edges per kb_fill block

typedef __attribute__((ext_vector_type(8))) short short8;
typedef __attribute__((ext_vector_type(8))) unsigned short us8;
typedef __attribute__((ext_vector_type(4))) float f32x4;

// ---- monotonic float<->uint encoding for atomicMax on floats ----
__device__ __forceinline__ unsigned enc_max(float f) {
    unsigned u = __float_as_uint(f);
    return ((int)u >= 0) ? (u | 0x80000000u) : ~u;
}
__device__ __forceinline__ float dec_max(unsigned u) {
    return (u & 0x80000000u) ? __uint_as_float(u ^ 0x80000000u)
                             : __uint_as_float(~u);
}

__device__ __forceinline__ float leaky(float v) {
    return v > 0.f ? v : LEAKY * v;
}

// fp32 -> bf16 (round-to-nearest-even), finite inputs
__device__ __forceinline__ unsigned short f2bf(float f) {
    unsigned u = __float_as_uint(f);
    u = (u + 0x7FFFu + ((u >> 16) & 1u)) >> 16;
    return (unsigned short)u;
}
__device__ __forceinline__ float bf2f(unsigned short u) {
    return __uint_as_float(((unsigned)u) << 16);
}

// ============================================================
// KB1: count edges per coarse bucket (LDS histogram, few global atomics)
// ============================================================
__global__ __launch_bounds__(256) void kb_count(
    const int* __restrict__ tgt, int* __restrict__ bcnt)
{
    __shared__ int hist[NB];
    for (int i = threadIdx.x; i < NB; i += 256) hist[i] = 0;
    __syncthreads();
    for (int e = blockIdx.x * 256 + threadIdx.x; e < E_EDGES; e += FB * 256)
        atomicAdd(&hist[tgt[e] >> BSH], 1);
    __syncthreads();
    for (int i = threadIdx.x; i < NB; i += 256) {
        int c = hist[i];
        if (c) atomicAdd(&bcnt[i], c);
    }
}

// ============================================================
// KB2: exclusive scan of 391 bucket counts -> bbase[392]; rowptr[N]=E
// ============================================================
__global__ __launch_bounds__(512) void kb_scan(
    const int* __restrict__ bcnt, int* __restrict__ bbase,
    int* __restrict__ rowptr)
{
    int t = threadIdx.x;
    int v = (t < NB) ? bcnt[t] : 0;
    int lane = t & 63, wv = t >> 6;
    int s = v;
#pragma unroll
    for (int off = 1; off < 64; off <<= 1) {
        int u = __shfl_up(s, off, 64);
        if (lane >= off) s += u;
    }
    __shared__ int ws[8];
    if (lane == 63) ws[wv] = s;
    __syncthreads();
    int add = 0;
    for (int w = 0; w < wv; w++) add += ws[w];
    int ex = add + s - v;
    if (t < NB) bbase[t] = ex;
    if (t == NB - 1) {
        bbase[NB] = ex + v;              // == E_EDGES
        rowptr[N_NODES] = ex + v;
    }
}

// ============================================================
// KB3: bucket the edges. Per-block LDS histogram -> one global
// reservation per (block,bucket) -> contiguous runs (low write-amp).
// Packed entry: src (16b) | tgt_local (7b) << 16.
// ============================================================
__global__ __launch_bounds__(256) void kb_fill(
    const int* __restrict__ src, const int* __restrict__ tgt,
    const int* __restrict__ bbase, int* __restrict__ bcur,
    int* __restrict__ ebkt)
{
    __shared__ int hist[NB];
    __shared__ int rbase[NB];
    int beg = blockIdx.x * FCH;
    int end = min(beg + FCH, E_EDGES);
    for (int i = threadIdx.x; i < NB; i += 256) hist[i] = 0;
    __syncthreads();
    for (int e = beg + threadIdx.x; e < end; e += 256)
        atomicAdd(&hist[tgt[e] >> BSH], 1);
    __syncthreads();
    for (int i = threadIdx.x; i < NB; i += 256) {
        int c = hist[i];
        rbase[i] = c ? (bbase[i] + atomicAdd(&bcur[i], c)) : 0;
    }
    __syncthreads();
    for (int i = threadIdx.x; i < NB; i += 256) hist[i] = 0;  // reuse as cursor
    __syncthreads();
    for (int e = beg + threadIdx.x; e < end; e += 256) {
        int tv = tgt[e], b = tv >> BSH;
        int off = atomicAdd(&hist[b], 1);
        ebkt[rbase[b] + off] = src[e] | ((tv & 127) << 16);
    }
}

// ============================================================
// KB4: fine sort within bucket -> rowptr + esrc. One block per bucket;
// all writes confined to the bucket's contiguous region (full-line WB).
// ============================================================
__global__ __launch_bounds__(256) void kb_sort(
    const int* __restrict__ bbase, const int* __restrict__ ebkt,
    int* __restrict__ rowptr, int* __restrict__ esrc)
{
    __shared__ int deg_l[128], excl_l[128], cur_l[128];
    __shared__ int wtot;
    int b    = blockIdx.x;
    int base = bbase[b];
    int cnt  = bbase[b + 1] - base;
    int tid  = threadIdx.x;
    if (tid < 128) { deg_l[tid] = 0; cur_l[tid] = 0; }
    __syncthreads();
    for (int j = tid; j < cnt; j += 256)
        atomicAdd(&deg_l[ebkt[base + j] >> 16], 1);
    __syncthreads();
    // exclusive scan of 128 (two waves + LDS carry)
    int v = (tid < 128) ? deg_l[tid] : 0;
    int lane = tid & 63, wv = tid >> 6;
    int s = v;
#pragma unroll
    for (int off = 1; off < 64; off <<= 1) {
        int u = __shfl_up(s, off, 64);
        if (lane >= off) s += u;
    }
    if (tid == 63) wtot = s;
    __syncthreads();
    if (tid < 128) {
        int ex = s - v + ((wv == 1) ? wtot : 0);
        excl_l[tid] = ex;
        int node = (b << BSH) + tid;
        if (node < N_NODES) rowptr[node] = base + ex;
    }
    __syncthreads();
    for (int j = tid; j < cnt; j += 256) {
        int p  = ebkt[base + j];
        int tl = p >> 16;
        int off = atomicAdd(&cur_l[tl], 1);
        esrc[base + excl_l[tl] + off] = p & 0xFFFF;
    }
}

// ============================================================
// K1: h = x @ W via mfma_f32_16x16x32_bf16, fp32 x converted inline.
// W staged into LDS pre-swizzled into B-fragment layout (32 KB).
// Epilogue: h stored as bf16 (hb); fused s/t logit dots.
// ============================================================
__global__ __launch_bounds__(256) void k1_mfma(
    const float* __restrict__ x, const float* __restrict__ W,
    const float* __restrict__ a_src, const float* __restrict__ a_tgt,
    unsigned short* __restrict__ hb, float* __restrict__ s,
    float* __restrict__ t)
{
    __shared__ unsigned short Wl[32 * 64 * 8];   // 32 KB
    const int tid = threadIdx.x;
    for (int idx = tid; idx < 2048; idx += 256) {
        int l  = idx & 63;
        int f  = idx >> 6;
        int nt = f >> 2, kc = f & 3;
        int kbase = kc * 32 + ((l >> 4) << 3);
        int col   = nt * 16 + (l & 15);
        unsigned short* dst = &Wl[idx * 8];
#pragma unroll
        for (int j = 0; j < 8; j++)
            dst[j] = f2bf(W[(kbase + j) * HD + col]);
    }
    __syncthreads();

    const int wave = tid >> 6, lane = tid & 63;
    const int quad = lane >> 4, rl = lane & 15;
    const int row0 = blockIdx.x * 64 + wave * 16;
    const int crow = min(row0 + rl, N_NODES - 1);

    short8 a[4];
    const float* xp = x + (size_t)crow * IN_DIM + quad * 8;
#pragma unroll
    for (int kc = 0; kc < 4; kc++) {
        float4 v0 = *(const float4*)(xp + kc * 32);
        float4 v1 = *(const float4*)(xp + kc * 32 + 4);
        short8 av;
        av[0] = (short)f2bf(v0.x); av[1] = (short)f2bf(v0.y);
        av[2] = (short)f2bf(v0.z); av[3] = (short)f2bf(v0.w);
        av[4] = (short)f2bf(v1.x); av[5] = (short)f2bf(v1.y);
        av[6] = (short)f2bf(v1.z); av[7] = (short)f2bf(v1.w);
        a[kc] = av;
    }

    float asv[8], atv[8];
#pragma unroll
    for (int nt = 0; nt < 8; nt++) {
        asv[nt] = a_src[nt * 16 + rl];
        atv[nt] = a_tgt[nt * 16 + rl];
    }

    float ps[4][4], pt[4][4];   // [head][r]
#pragma unroll
    for (int hh = 0; hh < 4; hh++)
#pragma unroll
        for (int r = 0; r < 4; r++) { ps[hh][r] = 0.f; pt[hh][r] = 0.f; }

#pragma unroll
    for (int nt = 0; nt < 8; nt++) {
        f32x4 acc = {0.f, 0.f, 0.f, 0.f};
#pragma unroll
        for (int kc = 0; kc < 4; kc++) {
            short8 b = *(const short8*)&Wl[((nt * 4 + kc) * 64 + lane) * 8];
            acc = __builtin_amdgcn_mfma_f32_16x16x32_bf16(a[kc], b, acc, 0, 0, 0);
        }
        const int ocol = nt * 16 + rl;
        const int hh   = nt >> 1;
#pragma unroll
        for (int r = 0; r < 4; r++) {
            int orow = row0 + quad * 4 + r;
            if (orow < N_NODES)
                hb[(size_t)orow * HD + ocol] = f2bf(acc[r]);
            ps[hh][r] = fmaf(acc[r], asv[nt], ps[hh][r]);
            pt[hh][r] = fmaf(acc[r], atv[nt], pt[hh][r]);
        }
    }

#pragma unroll
    for (int m = 1; m <= 8; m <<= 1) {
#pragma unroll
        for (int hh = 0; hh < 4; hh++)
#pragma unroll
            for (int r = 0; r < 4; r++) {
                ps[hh][r] += __shfl_xor(ps[hh][r], m, 64);
                pt[hh][r] += __shfl_xor(pt[hh][r], m, 64);
            }
    }
    if (rl == 0) {
#pragma unroll
        for (int r = 0; r < 4; r++) {
            int orow = row0 + quad * 4 + r;
            if (orow < N_NODES) {
#pragma unroll
                for (int hh = 0; hh < 4; hh++) {
                    s[orow * HEADS + hh] = ps[hh][r];
                    t[orow * HEADS + hh] = pt[hh][r];
                }
            }
        }
    }
}

// ============================================================
// K2: per-head max over NODES of s and t separately.
// ============================================================
#define K2_BLOCKS 32
__global__ __launch_bounds__(256) void k2_nodemax(
    const float* __restrict__ s, const float* __restrict__ t,
    unsigned* __restrict__ smax, unsigned* __restrict__ tmax)
{
    float sm0 = -INFINITY, sm1 = -INFINITY, sm2 = -INFINITY, sm3 = -INFINITY;
    float tm0 = -INFINITY, tm1 = -INFINITY, tm2 = -INFINITY, tm3 = -INFINITY;
    for (int n = blockIdx.x * 256 + threadIdx.x; n < N_NODES;
         n += K2_BLOCKS * 256) {
        float4 s4 = ((const float4*)s)[n];
        float4 t4 = ((const float4*)t)[n];
        sm0 = fmaxf(sm0, s4.x); sm1 = fmaxf(sm1, s4.y);
        sm2 = fmaxf(sm2, s4.z); sm3 = fmaxf(sm3, s4.w);
        tm0 = fmaxf(tm0, t4.x); tm1 = fmaxf(tm1, t4.y);
        tm2 = fmaxf(tm2, t4.z); tm3 = fmaxf(tm3, t4.w);
    }
#pragma unroll
    for (int m = 32; m >= 1; m >>= 1) {
        sm0 = fmaxf(sm0, __shfl_xor(sm0, m, 64));
        sm1 = fmaxf(sm1, __shfl_xor(sm1, m, 64));
        sm2 = fmaxf(sm2, __shfl_xor(sm2, m, 64));
        sm3 = fmaxf(sm3, __shfl_xor(sm3, m, 64));
        tm0 = fmaxf(tm0, __shfl_xor(tm0, m, 64));
        tm1 = fmaxf(tm1, __shfl_xor(tm1, m, 64));
        tm2 = fmaxf(tm2, __shfl_xor(tm2, m, 64));
        tm3 = fmaxf(tm3, __shfl_xor(tm3, m, 64));
    }
    __shared__ float red[4][8];
    int wid = threadIdx.x >> 6;
    if ((threadIdx.x & 63) == 0) {
        red[wid][0] = sm0; red[wid][1] = sm1; red[wid][2] = sm2; red[wid][3] = sm3;
        red[wid][4] = tm0; red[wid][5] = tm1; red[wid][6] = tm2; red[wid][7] = tm3;
    }
    __syncthreads();
    if (threadIdx.x < 8) {
        float v = fmaxf(fmaxf(red[0][threadIdx.x], red[1][threadIdx.x]),
                        fmaxf(red[2][threadIdx.x], red[3][threadIdx.x]));
        unsigned* dst = (threadIdx.x < 4) ? &smax[threadIdx.x]
                                          : &tmax[threadIdx.x - 4];
        atomicMax(dst, enc_max(v));
    }
}

// ============================================================
// K4: pull aggregation. 16 lanes per target node, 8 bf16 ch each (16 B).
// ============================================================
__global__ __launch_bounds__(256) void k4_pull(
    const int* __restrict__ rowptr, const int* __restrict__ esrc,
    const float* __restrict__ s, const float* __restrict__ t,
    const unsigned* __restrict__ smax, const unsigned* __restrict__ tmax,
    const unsigned short* __restrict__ hb, float* __restrict__ outp)
{
    int g = blockIdx.x * 256 + threadIdx.x;
    int node = g >> 4;
    int lane = g & 15;
    if (node >= N_NODES) return;
    int head = lane >> 2;                 // 4 lanes per head, 8 ch each
    int beg = rowptr[node];
    int end = rowptr[node + 1];
    float mx = leaky(dec_max(smax[head]) + dec_max(tmax[head]));
    float tv = t[node * HEADS + head];

    float a0 = 0.f, a1 = 0.f, a2 = 0.f, a3 = 0.f;
    float a4 = 0.f, a5 = 0.f, a6 = 0.f, a7 = 0.f, asum = 0.f;
    const unsigned short* hbase = hb + lane * 8;
    for (int j = beg; j < end; j++) {
        int si  = esrc[j];
        float sv = s[si * HEADS + head];
        float a  = __expf(leaky(sv + tv) - mx);
        us8 hv = *(const us8*)(hbase + (size_t)si * HD);
        a0 = fmaf(a, bf2f(hv[0]), a0);
        a1 = fmaf(a, bf2f(hv[1]), a1);
        a2 = fmaf(a, bf2f(hv[2]), a2);
        a3 = fmaf(a, bf2f(hv[3]), a3);
        a4 = fmaf(a, bf2f(hv[4]), a4);
        a5 = fmaf(a, bf2f(hv[5]), a5);
        a6 = fmaf(a, bf2f(hv[6]), a6);
        a7 = fmaf(a, bf2f(hv[7]), a7);
        asum += a;
    }
    float w = 1.0f / (asum + 1e-16f);
    float4* op = (float4*)(outp + (size_t)node * HD + lane * 8);
    op[0] = make_float4(a0 * w, a1 * w, a2 * w, a3 * w);
    op[1] = make_float4(a4 * w, a5 * w, a6 * w, a7 * w);
}

// ============================================================
// K5: BN stats: per-channel sum & sumsq over N rows
// ============================================================
__global__ __launch_bounds__(256) void k5_stats(
    const float* __restrict__ outp,
    float* __restrict__ bnsum, float* __restrict__ bnsq)
{
    int c    = threadIdx.x & 127;
    int half = threadIdx.x >> 7;
    int base = blockIdx.x * 128;
    int end  = min(base + 128, N_NODES);
    float sm = 0.f, sq = 0.f;
    for (int r = base + half; r < end; r += 2) {
        float v = outp[(size_t)r * HD + c];
        sm += v;
        sq = fmaf(v, v, sq);
    }
    unsafeAtomicAdd(&bnsum[c], sm);
    unsafeAtomicAdd(&bnsq[c], sq);
}

// ============================================================
// K6: BN apply -> d_out
// ============================================================
__global__ __launch_bounds__(256) void k6_apply(
    const float* __restrict__ outp,
    const float* __restrict__ bnsum, const float* __restrict__ bnsq,
    const float* __restrict__ gamma, const float* __restrict__ beta,
    float* __restrict__ out)
{
    int c    = threadIdx.x & 127;
    int half = threadIdx.x >> 7;
    int base = blockIdx.x * 128;
    int end  = min(base + 128, N_NODES);
    float inv_n = 1.0f / (float)N_NODES;
    float mean = bnsum[c] * inv_n;
    float var  = bnsq[c] * inv_n - mean * mean;
    float scale = gamma[c] * rsqrtf(var + BN_EPS);
    float shift = beta[c] - mean * scale;
    for (int r = base + half; r < end; r += 2) {
        size_t i = (size_t)r * HD + c;
        out[i] = fmaf(outp[i], scale, shift);
    }
}

// ============================================================
extern "C" void kernel_launch(void* const* d_in, const int* in_sizes, int n_in,
                              void* d_out, int out_size, void* d_ws, size_t ws_size,
                              hipStream_t stream)
{
    const float* x     = (const float*)d_in[0];
    const float* W     = (const float*)d_in[1];
    const float* a_src = (const float*)d_in[2];
    const float* a_tgt = (const float*)d_in[3];
    const float* gamma = (const float*)d_in[4];
    const float* beta  = (const float*)d_in[5];
    const int*   eidx  = (const int*)d_in[6];
    const int* src = eidx;
    const int* tgt = eidx + E_EDGES;
    float* out = (float*)d_out;

    // workspace layout (4-byte words)
    unsigned short* hb = (unsigned short*)d_ws;         // 6,400,000 ushort
    float* s      = (float*)d_ws + 3200000;             //   200,000
    float* t      = s + (size_t)N_NODES * HEADS;        //   200,000
    float* outp   = t + (size_t)N_NODES * HEADS;        // 6,400,000
    // ebkt aliases outp: dead before k4_pull writes outp
    int*   ebkt   = (int*)outp;                         //   800,000
    int*   esrc   = (int*)(outp + (size_t)N_NODES * HD);//   800,000
    int*   rowptr = esrc + E_EDGES;                     //    50,001
    int*   bbase  = rowptr + N_NODES + 1;               //       392
    // ---- zero-init region (single memset) ----
    int*      bcnt  = bbase + 392;                      //       392
    int*      bcur  = bcnt + 392;                       //       392
    unsigned* smax  = (unsigned*)(bcur + 392);          //         4
    unsigned* tmax  = smax + 4;                         //         4
    float*    bnsum = (float*)(tmax + 4);               //       128
    float*    bnsq  = bnsum + HD;                       //       128
    size_t zero_bytes = (392 + 392 + 8 + HD + HD) * 4;
    hipMemsetAsync(bcnt, 0, zero_bytes, stream);

    // CSR build (bucketed counting sort)
    kb_count<<<FB, 256, 0, stream>>>(tgt, bcnt);
    kb_scan<<<1, 512, 0, stream>>>(bcnt, bbase, rowptr);
    kb_fill<<<FB, 256, 0, stream>>>(src, tgt, bbase, bcur, ebkt);
    kb_sort<<<NB, 256, 0, stream>>>(bbase, ebkt, rowptr, esrc);

    // GEMM (bf16 MFMA) with fused bf16-h store + s/t logits
    k1_mfma<<<(N_NODES + 63) / 64, 256, 0, stream>>>(x, W, a_src, a_tgt,
                                                     hb, s, t);
    // per-head node max of s,t (upper bound on edge max; shift cancels)
    k2_nodemax<<<K2_BLOCKS, 256, 0, stream>>>(s, t, smax, tmax);
    // pull aggregation (no atomics), bf16 h gather
    long long k4_threads = (long long)N_NODES * 16;
    k4_pull<<<(unsigned)((k4_threads + 255) / 256), 256, 0, stream>>>(
        rowptr, esrc, s, t, smax, tmax, hb, outp);
    // BN
    k5_stats<<<(N_NODES + 127) / 128, 256, 0, stream>>>(outp, bnsum, bnsq);
    k6_apply<<<(N_NODES + 127) / 128, 256, 0, stream>>>(outp, bnsum, bnsq,
                                                        gamma, beta, out);
}

// Round 8
// 206.348 us; speedup vs baseline: 11.3109x; 1.1897x over previous
//
#include <hip/hip_runtime.h>
#include <math.h>

#define N_NODES 50000
#define E_EDGES 800000
#define IN_DIM 128
#define HEADS 4
#define OUT_DIM 32
#define HD 128          // HEADS*OUT_DIM
#define LEAKY 0.4f
#define BN_EPS 1e-5f

// bucketed counting sort params: bucket = tgt >> 7 (128 targets/bucket)
#define BSH 7
#define NB ((N_NODES + 127) >> BSH)     // 391
#define FB 196                           // kb_fill blocks
#define FCH 4096                         // edges per kb_fill block
#define SRTCAP 3072                      // LDS staging cap in kb_sort

typedef __attribute__((ext_vector_type(8))) short short8;
typedef __attribute__((ext_vector_type(8))) unsigned short us8;
typedef __attribute__((ext_vector_type(4))) float f32x4;

// ---- monotonic float<->uint encoding for atomicMax on floats ----
__device__ __forceinline__ unsigned enc_max(float f) {
    unsigned u = __float_as_uint(f);
    return ((int)u >= 0) ? (u | 0x80000000u) : ~u;
}
__device__ __forceinline__ float dec_max(unsigned u) {
    return (u & 0x80000000u) ? __uint_as_float(u ^ 0x80000000u)
                             : __uint_as_float(~u);
}

__device__ __forceinline__ float leaky(float v) {
    return v > 0.f ? v : LEAKY * v;
}

// fp32 -> bf16 (round-to-nearest-even), finite inputs
__device__ __forceinline__ unsigned short f2bf(float f) {
    unsigned u = __float_as_uint(f);
    u = (u + 0x7FFFu + ((u >> 16) & 1u)) >> 16;
    return (unsigned short)u;
}
__device__ __forceinline__ float bf2f(unsigned short u) {
    return __uint_as_float(((unsigned)u) << 16);
}

// ============================================================
// KB1: count edges per coarse bucket (LDS histogram)
// ============================================================
__global__ __launch_bounds__(256) void kb_count(
    const int* __restrict__ tgt, int* __restrict__ bcnt)
{
    __shared__ int hist[NB];
    for (int i = threadIdx.x; i < NB; i += 256) hist[i] = 0;
    __syncthreads();
    for (int e = blockIdx.x * 256 + threadIdx.x; e < E_EDGES; e += FB * 256)
        atomicAdd(&hist[tgt[e] >> BSH], 1);
    __syncthreads();
    for (int i = threadIdx.x; i < NB; i += 256) {
        int c = hist[i];
        if (c) atomicAdd(&bcnt[i], c);
    }
}

// ============================================================
// KB2: exclusive scan of 391 bucket counts -> bbase[392]; rowptr[N]=E
// ============================================================
__global__ __launch_bounds__(512) void kb_scan(
    const int* __restrict__ bcnt, int* __restrict__ bbase,
    int* __restrict__ rowptr)
{
    int t = threadIdx.x;
    int v = (t < NB) ? bcnt[t] : 0;
    int lane = t & 63, wv = t >> 6;
    int s = v;
#pragma unroll
    for (int off = 1; off < 64; off <<= 1) {
        int u = __shfl_up(s, off, 64);
        if (lane >= off) s += u;
    }
    __shared__ int ws[8];
    if (lane == 63) ws[wv] = s;
    __syncthreads();
    int add = 0;
    for (int w = 0; w < wv; w++) add += ws[w];
    int ex = add + s - v;
    if (t < NB) bbase[t] = ex;
    if (t == NB - 1) {
        bbase[NB] = ex + v;              // == E_EDGES
        rowptr[N_NODES] = ex + v;
    }
}

// ============================================================
// KB3: bucket the edges (contiguous reservations, low write-amp).
// Packed entry: src (16b) | tgt_local (7b) << 16.
// ============================================================
__global__ __launch_bounds__(256) void kb_fill(
    const int* __restrict__ src, const int* __restrict__ tgt,
    const int* __restrict__ bbase, int* __restrict__ bcur,
    int* __restrict__ ebkt)
{
    __shared__ int hist[NB];
    __shared__ int rbase[NB];
    int beg = blockIdx.x * FCH;
    int end = min(beg + FCH, E_EDGES);
    for (int i = threadIdx.x; i < NB; i += 256) hist[i] = 0;
    __syncthreads();
    for (int e = beg + threadIdx.x; e < end; e += 256)
        atomicAdd(&hist[tgt[e] >> BSH], 1);
    __syncthreads();
    for (int i = threadIdx.x; i < NB; i += 256) {
        int c = hist[i];
        rbase[i] = c ? (bbase[i] + atomicAdd(&bcur[i], c)) : 0;
    }
    __syncthreads();
    for (int i = threadIdx.x; i < NB; i += 256) hist[i] = 0;  // reuse as cursor
    __syncthreads();
    for (int e = beg + threadIdx.x; e < end; e += 256) {
        int tv = tgt[e], b = tv >> BSH;
        int off = atomicAdd(&hist[b], 1);
        ebkt[rbase[b] + off] = src[e] | ((tv & 127) << 16);
    }
}

// ============================================================
// KB4: fine sort within bucket -> rowptr + esrc (ushort).
// Stages bucket in LDS and coarse-sorts by src-chunk (src>>9) first, so
// each node's edge list is ~ascending in src -> sliding-window gather
// locality in k4_pull. Fallback to unsorted path if bucket > SRTCAP.
// ============================================================
__global__ __launch_bounds__(256) void kb_sort(
    const int* __restrict__ bbase, const int* __restrict__ ebkt,
    int* __restrict__ rowptr, unsigned short* __restrict__ esrc)
{
    __shared__ int ebl[SRTCAP];
    __shared__ int srt[SRTCAP];
    __shared__ int bins[128];                 // 98 chunk bins used
    __shared__ int deg_l[128], excl_l[128], cur_l[128];
    __shared__ int wtot, btot;
    int b    = blockIdx.x;
    int base = bbase[b];
    int cnt  = bbase[b + 1] - base;
    int tid  = threadIdx.x;
    int lane = tid & 63, wv = tid >> 6;
    if (tid < 128) { deg_l[tid] = 0; cur_l[tid] = 0; bins[tid] = 0; }
    __syncthreads();

    const bool fit = (cnt <= SRTCAP);         // block-uniform
    if (fit) {
        for (int j = tid; j < cnt; j += 256) {
            int p = ebkt[base + j];
            ebl[j] = p;
            atomicAdd(&bins[(p & 0xFFFF) >> 9], 1);
        }
        __syncthreads();
        // exclusive scan of 128 chunk bins -> cursors
        int v = (tid < 128) ? bins[tid] : 0;
        int s = v;
#pragma unroll
        for (int off = 1; off < 64; off <<= 1) {
            int u = __shfl_up(s, off, 64);
            if (lane >= off) s += u;
        }
        if (tid == 63) btot = s;
        __syncthreads();
        if (tid < 128) bins[tid] = s - v + ((wv == 1) ? btot : 0);
        __syncthreads();
        for (int j = tid; j < cnt; j += 256) {
            int p = ebl[j];
            int pos = atomicAdd(&bins[(p & 0xFFFF) >> 9], 1);
            srt[pos] = p;
        }
        __syncthreads();
        for (int j = tid; j < cnt; j += 256)
            atomicAdd(&deg_l[srt[j] >> 16], 1);
        __syncthreads();
    } else {
        for (int j = tid; j < cnt; j += 256)
            atomicAdd(&deg_l[ebkt[base + j] >> 16], 1);
        __syncthreads();
    }

    // exclusive scan of 128 target degrees
    int v = (tid < 128) ? deg_l[tid] : 0;
    int s = v;
#pragma unroll
    for (int off = 1; off < 64; off <<= 1) {
        int u = __shfl_up(s, off, 64);
        if (lane >= off) s += u;
    }
    if (tid == 63) wtot = s;
    __syncthreads();
    if (tid < 128) {
        int ex = s - v + ((wv == 1) ? wtot : 0);
        excl_l[tid] = ex;
        int node = (b << BSH) + tid;
        if (node < N_NODES) rowptr[node] = base + ex;
    }
    __syncthreads();
    if (fit) {
        for (int j = tid; j < cnt; j += 256) {
            int p  = srt[j];
            int tl = p >> 16;
            int off = atomicAdd(&cur_l[tl], 1);
            esrc[base + excl_l[tl] + off] = (unsigned short)(p & 0xFFFF);
        }
    } else {
        for (int j = tid; j < cnt; j += 256) {
            int p  = ebkt[base + j];
            int tl = p >> 16;
            int off = atomicAdd(&cur_l[tl], 1);
            esrc[base + excl_l[tl] + off] = (unsigned short)(p & 0xFFFF);
        }
    }
}

// ============================================================
// K1: h = x @ W via mfma_f32_16x16x32_bf16, fp32 x converted inline.
// W staged into LDS pre-swizzled into B-fragment layout (32 KB).
// Epilogue: h stored as bf16 (hb); fused s/t logit dots.
// ============================================================
__global__ __launch_bounds__(256) void k1_mfma(
    const float* __restrict__ x, const float* __restrict__ W,
    const float* __restrict__ a_src, const float* __restrict__ a_tgt,
    unsigned short* __restrict__ hb, float* __restrict__ s,
    float* __restrict__ t)
{
    __shared__ unsigned short Wl[32 * 64 * 8];   // 32 KB
    const int tid = threadIdx.x;
    for (int idx = tid; idx < 2048; idx += 256) {
        int l  = idx & 63;
        int f  = idx >> 6;
        int nt = f >> 2, kc = f & 3;
        int kbase = kc * 32 + ((l >> 4) << 3);
        int col   = nt * 16 + (l & 15);
        unsigned short* dst = &Wl[idx * 8];
#pragma unroll
        for (int j = 0; j < 8; j++)
            dst[j] = f2bf(W[(kbase + j) * HD + col]);
    }
    __syncthreads();

    const int wave = tid >> 6, lane = tid & 63;
    const int quad = lane >> 4, rl = lane & 15;
    const int row0 = blockIdx.x * 64 + wave * 16;
    const int crow = min(row0 + rl, N_NODES - 1);

    short8 a[4];
    const float* xp = x + (size_t)crow * IN_DIM + quad * 8;
#pragma unroll
    for (int kc = 0; kc < 4; kc++) {
        float4 v0 = *(const float4*)(xp + kc * 32);
        float4 v1 = *(const float4*)(xp + kc * 32 + 4);
        short8 av;
        av[0] = (short)f2bf(v0.x); av[1] = (short)f2bf(v0.y);
        av[2] = (short)f2bf(v0.z); av[3] = (short)f2bf(v0.w);
        av[4] = (short)f2bf(v1.x); av[5] = (short)f2bf(v1.y);
        av[6] = (short)f2bf(v1.z); av[7] = (short)f2bf(v1.w);
        a[kc] = av;
    }

    float asv[8], atv[8];
#pragma unroll
    for (int nt = 0; nt < 8; nt++) {
        asv[nt] = a_src[nt * 16 + rl];
        atv[nt] = a_tgt[nt * 16 + rl];
    }

    float ps[4][4], pt[4][4];   // [head][r]
#pragma unroll
    for (int hh = 0; hh < 4; hh++)
#pragma unroll
        for (int r = 0; r < 4; r++) { ps[hh][r] = 0.f; pt[hh][r] = 0.f; }

#pragma unroll
    for (int nt = 0; nt < 8; nt++) {
        f32x4 acc = {0.f, 0.f, 0.f, 0.f};
#pragma unroll
        for (int kc = 0; kc < 4; kc++) {
            short8 b = *(const short8*)&Wl[((nt * 4 + kc) * 64 + lane) * 8];
            acc = __builtin_amdgcn_mfma_f32_16x16x32_bf16(a[kc], b, acc, 0, 0, 0);
        }
        const int ocol = nt * 16 + rl;
        const int hh   = nt >> 1;
#pragma unroll
        for (int r = 0; r < 4; r++) {
            int orow = row0 + quad * 4 + r;
            if (orow < N_NODES)
                hb[(size_t)orow * HD + ocol] = f2bf(acc[r]);
            ps[hh][r] = fmaf(acc[r], asv[nt], ps[hh][r]);
            pt[hh][r] = fmaf(acc[r], atv[nt], pt[hh][r]);
        }
    }

#pragma unroll
    for (int m = 1; m <= 8; m <<= 1) {
#pragma unroll
        for (int hh = 0; hh < 4; hh++)
#pragma unroll
            for (int r = 0; r < 4; r++) {
                ps[hh][r] += __shfl_xor(ps[hh][r], m, 64);
                pt[hh][r] += __shfl_xor(pt[hh][r], m, 64);
            }
    }
    if (rl == 0) {
#pragma unroll
        for (int r = 0; r < 4; r++) {
            int orow = row0 + quad * 4 + r;
            if (orow < N_NODES) {
#pragma unroll
                for (int hh = 0; hh < 4; hh++) {
                    s[orow * HEADS + hh] = ps[hh][r];
                    t[orow * HEADS + hh] = pt[hh][r];
                }
            }
        }
    }
}

// ============================================================
// K2: per-head max over NODES of s and t separately.
// ============================================================
#define K2_BLOCKS 32
__global__ __launch_bounds__(256) void k2_nodemax(
    const float* __restrict__ s, const float* __restrict__ t,
    unsigned* __restrict__ smax, unsigned* __restrict__ tmax)
{
    float sm0 = -INFINITY, sm1 = -INFINITY, sm2 = -INFINITY, sm3 = -INFINITY;
    float tm0 = -INFINITY, tm1 = -INFINITY, tm2 = -INFINITY, tm3 = -INFINITY;
    for (int n = blockIdx.x * 256 + threadIdx.x; n < N_NODES;
         n += K2_BLOCKS * 256) {
        float4 s4 = ((const float4*)s)[n];
        float4 t4 = ((const float4*)t)[n];
        sm0 = fmaxf(sm0, s4.x); sm1 = fmaxf(sm1, s4.y);
        sm2 = fmaxf(sm2, s4.z); sm3 = fmaxf(sm3, s4.w);
        tm0 = fmaxf(tm0, t4.x); tm1 = fmaxf(tm1, t4.y);
        tm2 = fmaxf(tm2, t4.z); tm3 = fmaxf(tm3, t4.w);
    }
#pragma unroll
    for (int m = 32; m >= 1; m >>= 1) {
        sm0 = fmaxf(sm0, __shfl_xor(sm0, m, 64));
        sm1 = fmaxf(sm1, __shfl_xor(sm1, m, 64));
        sm2 = fmaxf(sm2, __shfl_xor(sm2, m, 64));
        sm3 = fmaxf(sm3, __shfl_xor(sm3, m, 64));
        tm0 = fmaxf(tm0, __shfl_xor(tm0, m, 64));
        tm1 = fmaxf(tm1, __shfl_xor(tm1, m, 64));
        tm2 = fmaxf(tm2, __shfl_xor(tm2, m, 64));
        tm3 = fmaxf(tm3, __shfl_xor(tm3, m, 64));
    }
    __shared__ float red[4][8];
    int wid = threadIdx.x >> 6;
    if ((threadIdx.x & 63) == 0) {
        red[wid][0] = sm0; red[wid][1] = sm1; red[wid][2] = sm2; red[wid][3] = sm3;
        red[wid][4] = tm0; red[wid][5] = tm1; red[wid][6] = tm2; red[wid][7] = tm3;
    }
    __syncthreads();
    if (threadIdx.x < 8) {
        float v = fmaxf(fmaxf(red[0][threadIdx.x], red[1][threadIdx.x]),
                        fmaxf(red[2][threadIdx.x], red[3][threadIdx.x]));
        unsigned* dst = (threadIdx.x < 4) ? &smax[threadIdx.x]
                                          : &tmax[threadIdx.x - 4];
        atomicMax(dst, enc_max(v));
    }
}

// ============================================================
// K4: pull aggregation. 16 lanes per target node, 8 bf16 ch each (16 B).
// esrc is src-ascending per node -> sliding-window gather locality.
// Output stored bf16.
// ============================================================
__global__ __launch_bounds__(256) void k4_pull(
    const int* __restrict__ rowptr, const unsigned short* __restrict__ esrc,
    const float* __restrict__ s, const float* __restrict__ t,
    const unsigned* __restrict__ smax, const unsigned* __restrict__ tmax,
    const unsigned short* __restrict__ hb, unsigned short* __restrict__ outpb)
{
    int g = blockIdx.x * 256 + threadIdx.x;
    int node = g >> 4;
    int lane = g & 15;
    if (node >= N_NODES) return;
    int head = lane >> 2;                 // 4 lanes per head, 8 ch each
    int beg = rowptr[node];
    int end = rowptr[node + 1];
    float mx = leaky(dec_max(smax[head]) + dec_max(tmax[head]));
    float tv = t[node * HEADS + head];

    float a0 = 0.f, a1 = 0.f, a2 = 0.f, a3 = 0.f;
    float a4 = 0.f, a5 = 0.f, a6 = 0.f, a7 = 0.f, asum = 0.f;
    const unsigned short* hbase = hb + lane * 8;
#pragma unroll 2
    for (int j = beg; j < end; j++) {
        int si  = esrc[j];
        float sv = s[si * HEADS + head];
        float a  = __expf(leaky(sv + tv) - mx);
        us8 hv = *(const us8*)(hbase + (size_t)si * HD);
        a0 = fmaf(a, bf2f(hv[0]), a0);
        a1 = fmaf(a, bf2f(hv[1]), a1);
        a2 = fmaf(a, bf2f(hv[2]), a2);
        a3 = fmaf(a, bf2f(hv[3]), a3);
        a4 = fmaf(a, bf2f(hv[4]), a4);
        a5 = fmaf(a, bf2f(hv[5]), a5);
        a6 = fmaf(a, bf2f(hv[6]), a6);
        a7 = fmaf(a, bf2f(hv[7]), a7);
        asum += a;
    }
    float w = 1.0f / (asum + 1e-16f);
    us8 o;
    o[0] = f2bf(a0 * w); o[1] = f2bf(a1 * w);
    o[2] = f2bf(a2 * w); o[3] = f2bf(a3 * w);
    o[4] = f2bf(a4 * w); o[5] = f2bf(a5 * w);
    o[6] = f2bf(a6 * w); o[7] = f2bf(a7 * w);
    *(us8*)(outpb + (size_t)node * HD + lane * 8) = o;
}

// ============================================================
// K5: BN stats from bf16 outp: per-channel sum & sumsq
// ============================================================
__global__ __launch_bounds__(256) void k5_stats(
    const unsigned short* __restrict__ outpb,
    float* __restrict__ bnsum, float* __restrict__ bnsq)
{
    __shared__ float lsum[HD], lsq[HD];
    int c8  = threadIdx.x & 15;          // channel octet
    int grp = threadIdx.x >> 4;          // row subgroup 0..15
    if (threadIdx.x < HD) { lsum[threadIdx.x] = 0.f; lsq[threadIdx.x] = 0.f; }
    __syncthreads();
    int base = blockIdx.x * 256;
    int end  = min(base + 256, N_NODES);
    float sm[8], sq[8];
#pragma unroll
    for (int i = 0; i < 8; i++) { sm[i] = 0.f; sq[i] = 0.f; }
    for (int r = base + grp; r < end; r += 16) {
        us8 v = *(const us8*)(outpb + (size_t)r * HD + c8 * 8);
#pragma unroll
        for (int i = 0; i < 8; i++) {
            float f = bf2f(v[i]);
            sm[i] += f;
            sq[i] = fmaf(f, f, sq[i]);
        }
    }
#pragma unroll
    for (int i = 0; i < 8; i++) {
        atomicAdd(&lsum[c8 * 8 + i], sm[i]);
        atomicAdd(&lsq[c8 * 8 + i], sq[i]);
    }
    __syncthreads();
    if (threadIdx.x < HD) {
        unsafeAtomicAdd(&bnsum[threadIdx.x], lsum[threadIdx.x]);
        unsafeAtomicAdd(&bnsq[threadIdx.x], lsq[threadIdx.x]);
    }
}

// ============================================================
// K6: BN apply (bf16 in, fp32 out) -> d_out
// ============================================================
__global__ __launch_bounds__(256) void k6_apply(
    const unsigned short* __restrict__ outpb,
    const float* __restrict__ bnsum, const float* __restrict__ bnsq,
    const float* __restrict__ gamma, const float* __restrict__ beta,
    float* __restrict__ out)
{
    int c8  = threadIdx.x & 15;
    int grp = threadIdx.x >> 4;
    int base = blockIdx.x * 256;
    int end  = min(base + 256, N_NODES);
    float inv_n = 1.0f / (float)N_NODES;
    float scale[8], shift[8];
#pragma unroll
    for (int i = 0; i < 8; i++) {
        int c = c8 * 8 + i;
        float mean = bnsum[c] * inv_n;
        float var  = bnsq[c] * inv_n - mean * mean;
        float sc   = gamma[c] * rsqrtf(var + BN_EPS);
        scale[i] = sc;
        shift[i] = beta[c] - mean * sc;
    }
    for (int r = base + grp; r < end; r += 16) {
        us8 v = *(const us8*)(outpb + (size_t)r * HD + c8 * 8);
        float4 o0, o1;
        o0.x = fmaf(bf2f(v[0]), scale[0], shift[0]);
        o0.y = fmaf(bf2f(v[1]), scale[1], shift[1]);
        o0.z = fmaf(bf2f(v[2]), scale[2], shift[2]);
        o0.w = fmaf(bf2f(v[3]), scale[3], shift[3]);
        o1.x = fmaf(bf2f(v[4]), scale[4], shift[4]);
        o1.y = fmaf(bf2f(v[5]), scale[5], shift[5]);
        o1.z = fmaf(bf2f(v[6]), scale[6], shift[6]);
        o1.w = fmaf(bf2f(v[7]), scale[7], shift[7]);
        float* op = out + (size_t)r * HD + c8 * 8;
        ((float4*)op)[0] = o0;
        ((float4*)op)[1] = o1;
    }
}

// ============================================================
extern "C" void kernel_launch(void* const* d_in, const int* in_sizes, int n_in,
                              void* d_out, int out_size, void* d_ws, size_t ws_size,
                              hipStream_t stream)
{
    const float* x     = (const float*)d_in[0];
    const float* W     = (const float*)d_in[1];
    const float* a_src = (const float*)d_in[2];
    const float* a_tgt = (const float*)d_in[3];
    const float* gamma = (const float*)d_in[4];
    const float* beta  = (const float*)d_in[5];
    const int*   eidx  = (const int*)d_in[6];
    const int* src = eidx;
    const int* tgt = eidx + E_EDGES;
    float* out = (float*)d_out;

    // workspace layout
    unsigned short* hb    = (unsigned short*)d_ws;          // 6.4M ushort
    float*          s     = (float*)d_ws + 3200000;         // 200K float
    float*          t     = s + (size_t)N_NODES * HEADS;    // 200K float
    unsigned short* outpb = (unsigned short*)(t + (size_t)N_NODES * HEADS); // 6.4M us
    int*            ebkt  = (int*)outpb;                    // 800K int (aliases outpb)
    unsigned short* esrc  = outpb + 6400000;                // 800K ushort
    int*            rowptr= (int*)(esrc + E_EDGES);         // 50,001 int
    int*            bbase = rowptr + N_NODES + 1;           // 392
    // ---- zero-init region (single memset) ----
    int*      bcnt  = bbase + 392;                          // 392
    int*      bcur  = bcnt + 392;                           // 392
    unsigned* smax  = (unsigned*)(bcur + 392);              // 4
    unsigned* tmax  = smax + 4;                             // 4
    float*    bnsum = (float*)(tmax + 4);                   // 128
    float*    bnsq  = bnsum + HD;                           // 128
    size_t zero_bytes = (392 + 392 + 8 + HD + HD) * 4;
    hipMemsetAsync(bcnt, 0, zero_bytes, stream);

    // CSR build (bucketed counting sort, src-ordered fine lists)
    kb_count<<<FB, 256, 0, stream>>>(tgt, bcnt);
    kb_scan<<<1, 512, 0, stream>>>(bcnt, bbase, rowptr);
    kb_fill<<<FB, 256, 0, stream>>>(src, tgt, bbase, bcur, ebkt);
    kb_sort<<<NB, 256, 0, stream>>>(bbase, ebkt, rowptr, esrc);

    // GEMM (bf16 MFMA) with fused bf16-h store + s/t logits
    k1_mfma<<<(N_NODES + 63) / 64, 256, 0, stream>>>(x, W, a_src, a_tgt,
                                                     hb, s, t);
    // per-head node max of s,t (upper bound on edge max; shift cancels)
    k2_nodemax<<<K2_BLOCKS, 256, 0, stream>>>(s, t, smax, tmax);
    // pull aggregation (no atomics), bf16 h gather, bf16 out
    long long k4_threads = (long long)N_NODES * 16;
    k4_pull<<<(unsigned)((k4_threads + 255) / 256), 256, 0, stream>>>(
        rowptr, esrc, s, t, smax, tmax, hb, outpb);
    // BN
    k5_stats<<<(N_NODES + 255) / 256, 256, 0, stream>>>(outpb, bnsum, bnsq);
    k6_apply<<<(N_NODES + 255) / 256, 256, 0, stream>>>(outpb, bnsum, bnsq,
                                                        gamma, beta, out);
}

// Round 9
// 199.059 us; speedup vs baseline: 11.7250x; 1.0366x over previous
//
#include <hip/hip_runtime.h>
#include <math.h>

#define N_NODES 50000
#define E_EDGES 800000
#define IN_DIM 128
#define HEADS 4
#define OUT_DIM 32
#define HD 128          // HEADS*OUT_DIM
#define LEAKY 0.4f
#define BN_EPS 1e-5f

// bucketed counting sort params: bucket = tgt >> 7 (128 targets/bucket)
#define BSH 7
#define NB ((N_NODES + 127) >> BSH)     // 391
#define FB 196                           // kb_fill blocks
#define FCH 4096                         // edges per kb_fill block
#define PCAP 2560                        // padded bucket capacity (mean 2048, sd 45)
#define SRTCAP 3072                      // LDS staging cap in kb_sort

typedef __attribute__((ext_vector_type(8))) short short8;
typedef __attribute__((ext_vector_type(8))) unsigned short us8;
typedef __attribute__((ext_vector_type(4))) float f32x4;

// ---- monotonic float<->uint encoding for atomicMax on floats ----
__device__ __forceinline__ unsigned enc_max(float f) {
    unsigned u = __float_as_uint(f);
    return ((int)u >= 0) ? (u | 0x80000000u) : ~u;
}
__device__ __forceinline__ float dec_max(unsigned u) {
    return (u & 0x80000000u) ? __uint_as_float(u ^ 0x80000000u)
                             : __uint_as_float(~u);
}

__device__ __forceinline__ float leaky(float v) {
    return v > 0.f ? v : LEAKY * v;
}

// fp32 -> bf16 (round-to-nearest-even), finite inputs
__device__ __forceinline__ unsigned short f2bf(float f) {
    unsigned u = __float_as_uint(f);
    u = (u + 0x7FFFu + ((u >> 16) & 1u)) >> 16;
    return (unsigned short)u;
}
__device__ __forceinline__ float bf2f(unsigned short u) {
    return __uint_as_float(((unsigned)u) << 16);
}

// ============================================================
// KB1: bucket the edges into FIXED padded regions (b*PCAP), reserving
// per-block runs with one global atomic per (block,bucket). No separate
// count pass needed. Packed entry: src (16b) | tgt_local (7b) << 16.
// ============================================================
__global__ __launch_bounds__(256) void kb_fill(
    const int* __restrict__ src, const int* __restrict__ tgt,
    int* __restrict__ bcur, int* __restrict__ ebkt)
{
    __shared__ int hist[NB];
    __shared__ int rbase[NB];
    int beg = blockIdx.x * FCH;
    int end = min(beg + FCH, E_EDGES);
    for (int i = threadIdx.x; i < NB; i += 256) hist[i] = 0;
    __syncthreads();
    for (int e = beg + threadIdx.x; e < end; e += 256)
        atomicAdd(&hist[tgt[e] >> BSH], 1);
    __syncthreads();
    for (int i = threadIdx.x; i < NB; i += 256) {
        int c = hist[i];
        if (c) {
            int r = atomicAdd(&bcur[i], c);
            rbase[i] = i * PCAP + min(r, PCAP);
        }
    }
    __syncthreads();
    for (int i = threadIdx.x; i < NB; i += 256) hist[i] = 0;  // reuse as cursor
    __syncthreads();
    for (int e = beg + threadIdx.x; e < end; e += 256) {
        int tv = tgt[e], b = tv >> BSH;
        int off = atomicAdd(&hist[b], 1);
        int idx = rbase[b] + off;
        if (idx < (b + 1) * PCAP)                 // overflow guard (never hits)
            ebkt[idx] = src[e] | ((tv & 127) << 16);
    }
}

// ============================================================
// KB2: exclusive scan of actual bucket counts -> bbase[392]; rowptr[N]=E
// ============================================================
__global__ __launch_bounds__(512) void kb_scan(
    const int* __restrict__ bcur, int* __restrict__ bbase,
    int* __restrict__ rowptr)
{
    int t = threadIdx.x;
    int v = (t < NB) ? min(bcur[t], PCAP) : 0;
    int lane = t & 63, wv = t >> 6;
    int s = v;
#pragma unroll
    for (int off = 1; off < 64; off <<= 1) {
        int u = __shfl_up(s, off, 64);
        if (lane >= off) s += u;
    }
    __shared__ int ws[8];
    if (lane == 63) ws[wv] = s;
    __syncthreads();
    int add = 0;
    for (int w = 0; w < wv; w++) add += ws[w];
    int ex = add + s - v;
    if (t < NB) bbase[t] = ex;
    if (t == NB - 1) {
        bbase[NB] = ex + v;              // == E_EDGES
        rowptr[N_NODES] = ex + v;
    }
}

// ============================================================
// KB3: fine sort within bucket -> rowptr + esrc (ushort), compacting
// padded region b*PCAP -> contiguous bbase[b]. Coarse-sorts by src-chunk
// (src>>9) so each node's list is ~ascending in src -> sliding-window
// gather locality in k4_pull.
// ============================================================
__global__ __launch_bounds__(256) void kb_sort(
    const int* __restrict__ bbase, const int* __restrict__ ebkt,
    int* __restrict__ rowptr, unsigned short* __restrict__ esrc)
{
    __shared__ int ebl[SRTCAP];
    __shared__ int srt[SRTCAP];
    __shared__ int bins[128];                 // 98 chunk bins used
    __shared__ int deg_l[128], excl_l[128], cur_l[128];
    __shared__ int wtot, btot;
    int b       = blockIdx.x;
    int base_in = b * PCAP;
    int base    = bbase[b];
    int cnt     = bbase[b + 1] - base;        // <= PCAP <= SRTCAP
    int tid  = threadIdx.x;
    int lane = tid & 63, wv = tid >> 6;
    if (tid < 128) { deg_l[tid] = 0; cur_l[tid] = 0; bins[tid] = 0; }
    __syncthreads();

    // stage + coarse src-chunk sort (always fits: cnt <= PCAP < SRTCAP)
    for (int j = tid; j < cnt; j += 256) {
        int p = ebkt[base_in + j];
        ebl[j] = p;
        atomicAdd(&bins[(p & 0xFFFF) >> 9], 1);
    }
    __syncthreads();
    {
        int v = (tid < 128) ? bins[tid] : 0;
        int s = v;
#pragma unroll
        for (int off = 1; off < 64; off <<= 1) {
            int u = __shfl_up(s, off, 64);
            if (lane >= off) s += u;
        }
        if (tid == 63) btot = s;
        __syncthreads();
        if (tid < 128) bins[tid] = s - v + ((wv == 1) ? btot : 0);
        __syncthreads();
    }
    for (int j = tid; j < cnt; j += 256) {
        int p = ebl[j];
        int pos = atomicAdd(&bins[(p & 0xFFFF) >> 9], 1);
        srt[pos] = p;
    }
    __syncthreads();
    for (int j = tid; j < cnt; j += 256)
        atomicAdd(&deg_l[srt[j] >> 16], 1);
    __syncthreads();

    // exclusive scan of 128 target degrees
    int v = (tid < 128) ? deg_l[tid] : 0;
    int s = v;
#pragma unroll
    for (int off = 1; off < 64; off <<= 1) {
        int u = __shfl_up(s, off, 64);
        if (lane >= off) s += u;
    }
    if (tid == 63) wtot = s;
    __syncthreads();
    if (tid < 128) {
        int ex = s - v + ((wv == 1) ? wtot : 0);
        excl_l[tid] = ex;
        int node = (b << BSH) + tid;
        if (node < N_NODES) rowptr[node] = base + ex;
    }
    __syncthreads();
    for (int j = tid; j < cnt; j += 256) {
        int p  = srt[j];
        int tl = p >> 16;
        int off = atomicAdd(&cur_l[tl], 1);
        esrc[base + excl_l[tl] + off] = (unsigned short)(p & 0xFFFF);
    }
}

// ============================================================
// K1: h = x @ W via mfma_f32_16x16x32_bf16, fp32 x converted inline.
// W staged into LDS pre-swizzled into B-fragment layout (32 KB).
// Epilogue: h stored as bf16 (hb); fused s/t logit dots.
// ============================================================
__global__ __launch_bounds__(256) void k1_mfma(
    const float* __restrict__ x, const float* __restrict__ W,
    const float* __restrict__ a_src, const float* __restrict__ a_tgt,
    unsigned short* __restrict__ hb, float* __restrict__ s,
    float* __restrict__ t)
{
    __shared__ unsigned short Wl[32 * 64 * 8];   // 32 KB
    const int tid = threadIdx.x;
    for (int idx = tid; idx < 2048; idx += 256) {
        int l  = idx & 63;
        int f  = idx >> 6;
        int nt = f >> 2, kc = f & 3;
        int kbase = kc * 32 + ((l >> 4) << 3);
        int col   = nt * 16 + (l & 15);
        unsigned short* dst = &Wl[idx * 8];
#pragma unroll
        for (int j = 0; j < 8; j++)
            dst[j] = f2bf(W[(kbase + j) * HD + col]);
    }
    __syncthreads();

    const int wave = tid >> 6, lane = tid & 63;
    const int quad = lane >> 4, rl = lane & 15;
    const int row0 = blockIdx.x * 64 + wave * 16;
    const int crow = min(row0 + rl, N_NODES - 1);

    short8 a[4];
    const float* xp = x + (size_t)crow * IN_DIM + quad * 8;
#pragma unroll
    for (int kc = 0; kc < 4; kc++) {
        float4 v0 = *(const float4*)(xp + kc * 32);
        float4 v1 = *(const float4*)(xp + kc * 32 + 4);
        short8 av;
        av[0] = (short)f2bf(v0.x); av[1] = (short)f2bf(v0.y);
        av[2] = (short)f2bf(v0.z); av[3] = (short)f2bf(v0.w);
        av[4] = (short)f2bf(v1.x); av[5] = (short)f2bf(v1.y);
        av[6] = (short)f2bf(v1.z); av[7] = (short)f2bf(v1.w);
        a[kc] = av;
    }

    float asv[8], atv[8];
#pragma unroll
    for (int nt = 0; nt < 8; nt++) {
        asv[nt] = a_src[nt * 16 + rl];
        atv[nt] = a_tgt[nt * 16 + rl];
    }

    float ps[4][4], pt[4][4];   // [head][r]
#pragma unroll
    for (int hh = 0; hh < 4; hh++)
#pragma unroll
        for (int r = 0; r < 4; r++) { ps[hh][r] = 0.f; pt[hh][r] = 0.f; }

#pragma unroll
    for (int nt = 0; nt < 8; nt++) {
        f32x4 acc = {0.f, 0.f, 0.f, 0.f};
#pragma unroll
        for (int kc = 0; kc < 4; kc++) {
            short8 b = *(const short8*)&Wl[((nt * 4 + kc) * 64 + lane) * 8];
            acc = __builtin_amdgcn_mfma_f32_16x16x32_bf16(a[kc], b, acc, 0, 0, 0);
        }
        const int ocol = nt * 16 + rl;
        const int hh   = nt >> 1;
#pragma unroll
        for (int r = 0; r < 4; r++) {
            int orow = row0 + quad * 4 + r;
            if (orow < N_NODES)
                hb[(size_t)orow * HD + ocol] = f2bf(acc[r]);
            ps[hh][r] = fmaf(acc[r], asv[nt], ps[hh][r]);
            pt[hh][r] = fmaf(acc[r], atv[nt], pt[hh][r]);
        }
    }

#pragma unroll
    for (int m = 1; m <= 8; m <<= 1) {
#pragma unroll
        for (int hh = 0; hh < 4; hh++)
#pragma unroll
            for (int r = 0; r < 4; r++) {
                ps[hh][r] += __shfl_xor(ps[hh][r], m, 64);
                pt[hh][r] += __shfl_xor(pt[hh][r], m, 64);
            }
    }
    if (rl == 0) {
#pragma unroll
        for (int r = 0; r < 4; r++) {
            int orow = row0 + quad * 4 + r;
            if (orow < N_NODES) {
#pragma unroll
                for (int hh = 0; hh < 4; hh++) {
                    s[orow * HEADS + hh] = ps[hh][r];
                    t[orow * HEADS + hh] = pt[hh][r];
                }
            }
        }
    }
}

// ============================================================
// K2: per-head max over NODES of s and t separately.
// ============================================================
#define K2_BLOCKS 32
__global__ __launch_bounds__(256) void k2_nodemax(
    const float* __restrict__ s, const float* __restrict__ t,
    unsigned* __restrict__ smax, unsigned* __restrict__ tmax)
{
    float sm0 = -INFINITY, sm1 = -INFINITY, sm2 = -INFINITY, sm3 = -INFINITY;
    float tm0 = -INFINITY, tm1 = -INFINITY, tm2 = -INFINITY, tm3 = -INFINITY;
    for (int n = blockIdx.x * 256 + threadIdx.x; n < N_NODES;
         n += K2_BLOCKS * 256) {
        float4 s4 = ((const float4*)s)[n];
        float4 t4 = ((const float4*)t)[n];
        sm0 = fmaxf(sm0, s4.x); sm1 = fmaxf(sm1, s4.y);
        sm2 = fmaxf(sm2, s4.z); sm3 = fmaxf(sm3, s4.w);
        tm0 = fmaxf(tm0, t4.x); tm1 = fmaxf(tm1, t4.y);
        tm2 = fmaxf(tm2, t4.z); tm3 = fmaxf(tm3, t4.w);
    }
#pragma unroll
    for (int m = 32; m >= 1; m >>= 1) {
        sm0 = fmaxf(sm0, __shfl_xor(sm0, m, 64));
        sm1 = fmaxf(sm1, __shfl_xor(sm1, m, 64));
        sm2 = fmaxf(sm2, __shfl_xor(sm2, m, 64));
        sm3 = fmaxf(sm3, __shfl_xor(sm3, m, 64));
        tm0 = fmaxf(tm0, __shfl_xor(tm0, m, 64));
        tm1 = fmaxf(tm1, __shfl_xor(tm1, m, 64));
        tm2 = fmaxf(tm2, __shfl_xor(tm2, m, 64));
        tm3 = fmaxf(tm3, __shfl_xor(tm3, m, 64));
    }
    __shared__ float red[4][8];
    int wid = threadIdx.x >> 6;
    if ((threadIdx.x & 63) == 0) {
        red[wid][0] = sm0; red[wid][1] = sm1; red[wid][2] = sm2; red[wid][3] = sm3;
        red[wid][4] = tm0; red[wid][5] = tm1; red[wid][6] = tm2; red[wid][7] = tm3;
    }
    __syncthreads();
    if (threadIdx.x < 8) {
        float v = fmaxf(fmaxf(red[0][threadIdx.x], red[1][threadIdx.x]),
                        fmaxf(red[2][threadIdx.x], red[3][threadIdx.x]));
        unsigned* dst = (threadIdx.x < 4) ? &smax[threadIdx.x]
                                          : &tmax[threadIdx.x - 4];
        atomicMax(dst, enc_max(v));
    }
}

// ============================================================
// K4: pull aggregation. 16 lanes per target node, 8 bf16 ch each (16 B).
// esrc is src-ascending per node -> sliding-window gather locality.
// Output stored bf16.
// ============================================================
__global__ __launch_bounds__(256) void k4_pull(
    const int* __restrict__ rowptr, const unsigned short* __restrict__ esrc,
    const float* __restrict__ s, const float* __restrict__ t,
    const unsigned* __restrict__ smax, const unsigned* __restrict__ tmax,
    const unsigned short* __restrict__ hb, unsigned short* __restrict__ outpb)
{
    int g = blockIdx.x * 256 + threadIdx.x;
    int node = g >> 4;
    int lane = g & 15;
    if (node >= N_NODES) return;
    int head = lane >> 2;                 // 4 lanes per head, 8 ch each
    int beg = rowptr[node];
    int end = rowptr[node + 1];
    float mx = leaky(dec_max(smax[head]) + dec_max(tmax[head]));
    float tv = t[node * HEADS + head];

    float a0 = 0.f, a1 = 0.f, a2 = 0.f, a3 = 0.f;
    float a4 = 0.f, a5 = 0.f, a6 = 0.f, a7 = 0.f, asum = 0.f;
    const unsigned short* hbase = hb + lane * 8;
#pragma unroll 2
    for (int j = beg; j < end; j++) {
        int si  = esrc[j];
        float sv = s[si * HEADS + head];
        float a  = __expf(leaky(sv + tv) - mx);
        us8 hv = *(const us8*)(hbase + (size_t)si * HD);
        a0 = fmaf(a, bf2f(hv[0]), a0);
        a1 = fmaf(a, bf2f(hv[1]), a1);
        a2 = fmaf(a, bf2f(hv[2]), a2);
        a3 = fmaf(a, bf2f(hv[3]), a3);
        a4 = fmaf(a, bf2f(hv[4]), a4);
        a5 = fmaf(a, bf2f(hv[5]), a5);
        a6 = fmaf(a, bf2f(hv[6]), a6);
        a7 = fmaf(a, bf2f(hv[7]), a7);
        asum += a;
    }
    float w = 1.0f / (asum + 1e-16f);
    us8 o;
    o[0] = f2bf(a0 * w); o[1] = f2bf(a1 * w);
    o[2] = f2bf(a2 * w); o[3] = f2bf(a3 * w);
    o[4] = f2bf(a4 * w); o[5] = f2bf(a5 * w);
    o[6] = f2bf(a6 * w); o[7] = f2bf(a7 * w);
    *(us8*)(outpb + (size_t)node * HD + lane * 8) = o;
}

// ============================================================
// K5: BN stats from bf16 outp: per-channel sum & sumsq
// ============================================================
__global__ __launch_bounds__(256) void k5_stats(
    const unsigned short* __restrict__ outpb,
    float* __restrict__ bnsum, float* __restrict__ bnsq)
{
    __shared__ float lsum[HD], lsq[HD];
    int c8  = threadIdx.x & 15;          // channel octet
    int grp = threadIdx.x >> 4;          // row subgroup 0..15
    if (threadIdx.x < HD) { lsum[threadIdx.x] = 0.f; lsq[threadIdx.x] = 0.f; }
    __syncthreads();
    int base = blockIdx.x * 256;
    int end  = min(base + 256, N_NODES);
    float sm[8], sq[8];
#pragma unroll
    for (int i = 0; i < 8; i++) { sm[i] = 0.f; sq[i] = 0.f; }
    for (int r = base + grp; r < end; r += 16) {
        us8 v = *(const us8*)(outpb + (size_t)r * HD + c8 * 8);
#pragma unroll
        for (int i = 0; i < 8; i++) {
            float f = bf2f(v[i]);
            sm[i] += f;
            sq[i] = fmaf(f, f, sq[i]);
        }
    }
#pragma unroll
    for (int i = 0; i < 8; i++) {
        atomicAdd(&lsum[c8 * 8 + i], sm[i]);
        atomicAdd(&lsq[c8 * 8 + i], sq[i]);
    }
    __syncthreads();
    if (threadIdx.x < HD) {
        unsafeAtomicAdd(&bnsum[threadIdx.x], lsum[threadIdx.x]);
        unsafeAtomicAdd(&bnsq[threadIdx.x], lsq[threadIdx.x]);
    }
}

// ============================================================
// K6: BN apply (bf16 in, fp32 out) -> d_out
// ============================================================
__global__ __launch_bounds__(256) void k6_apply(
    const unsigned short* __restrict__ outpb,
    const float* __restrict__ bnsum, const float* __restrict__ bnsq,
    const float* __restrict__ gamma, const float* __restrict__ beta,
    float* __restrict__ out)
{
    int c8  = threadIdx.x & 15;
    int grp = threadIdx.x >> 4;
    int base = blockIdx.x * 256;
    int end  = min(base + 256, N_NODES);
    float inv_n = 1.0f / (float)N_NODES;
    float scale[8], shift[8];
#pragma unroll
    for (int i = 0; i < 8; i++) {
        int c = c8 * 8 + i;
        float mean = bnsum[c] * inv_n;
        float var  = bnsq[c] * inv_n - mean * mean;
        float sc   = gamma[c] * rsqrtf(var + BN_EPS);
        scale[i] = sc;
        shift[i] = beta[c] - mean * sc;
    }
    for (int r = base + grp; r < end; r += 16) {
        us8 v = *(const us8*)(outpb + (size_t)r * HD + c8 * 8);
        float4 o0, o1;
        o0.x = fmaf(bf2f(v[0]), scale[0], shift[0]);
        o0.y = fmaf(bf2f(v[1]), scale[1], shift[1]);
        o0.z = fmaf(bf2f(v[2]), scale[2], shift[2]);
        o0.w = fmaf(bf2f(v[3]), scale[3], shift[3]);
        o1.x = fmaf(bf2f(v[4]), scale[4], shift[4]);
        o1.y = fmaf(bf2f(v[5]), scale[5], shift[5]);
        o1.z = fmaf(bf2f(v[6]), scale[6], shift[6]);
        o1.w = fmaf(bf2f(v[7]), scale[7], shift[7]);
        float* op = out + (size_t)r * HD + c8 * 8;
        ((float4*)op)[0] = o0;
        ((float4*)op)[1] = o1;
    }
}

// ============================================================
extern "C" void kernel_launch(void* const* d_in, const int* in_sizes, int n_in,
                              void* d_out, int out_size, void* d_ws, size_t ws_size,
                              hipStream_t stream)
{
    const float* x     = (const float*)d_in[0];
    const float* W     = (const float*)d_in[1];
    const float* a_src = (const float*)d_in[2];
    const float* a_tgt = (const float*)d_in[3];
    const float* gamma = (const float*)d_in[4];
    const float* beta  = (const float*)d_in[5];
    const int*   eidx  = (const int*)d_in[6];
    const int* src = eidx;
    const int* tgt = eidx + E_EDGES;
    float* out = (float*)d_out;

    // workspace layout
    unsigned short* hb    = (unsigned short*)d_ws;          // 6.4M ushort
    float*          s     = (float*)d_ws + 3200000;         // 200K float
    float*          t     = s + (size_t)N_NODES * HEADS;    // 200K float
    unsigned short* outpb = (unsigned short*)(t + (size_t)N_NODES * HEADS); // 6.4M us
    int*            ebkt  = (int*)outpb;                    // NB*PCAP=1.0M int (aliases outpb)
    unsigned short* esrc  = outpb + 6400000;                // 800K ushort
    int*            rowptr= (int*)(esrc + E_EDGES);         // 50,001 int
    int*            bbase = rowptr + N_NODES + 1;           // 392
    // ---- zero-init region (single memset) ----
    int*      bcur  = bbase + 392;                          // 392
    unsigned* smax  = (unsigned*)(bcur + 392);              // 4
    unsigned* tmax  = smax + 4;                             // 4
    float*    bnsum = (float*)(tmax + 4);                   // 128
    float*    bnsq  = bnsum + HD;                           // 128
    size_t zero_bytes = (392 + 8 + HD + HD) * 4;
    hipMemsetAsync(bcur, 0, zero_bytes, stream);

    // CSR build (padded-bucket counting sort, src-ordered fine lists)
    kb_fill<<<FB, 256, 0, stream>>>(src, tgt, bcur, ebkt);
    kb_scan<<<1, 512, 0, stream>>>(bcur, bbase, rowptr);
    kb_sort<<<NB, 256, 0, stream>>>(bbase, ebkt, rowptr, esrc);

    // GEMM (bf16 MFMA) with fused bf16-h store + s/t logits
    k1_mfma<<<(N_NODES + 63) / 64, 256, 0, stream>>>(x, W, a_src, a_tgt,
                                                     hb, s, t);
    // per-head node max of s,t (upper bound on edge max; shift cancels)
    k2_nodemax<<<K2_BLOCKS, 256, 0, stream>>>(s, t, smax, tmax);
    // pull aggregation (no atomics), bf16 h gather, bf16 out
    long long k4_threads = (long long)N_NODES * 16;
    k4_pull<<<(unsigned)((k4_threads + 255) / 256), 256, 0, stream>>>(
        rowptr, esrc, s, t, smax, tmax, hb, outpb);
    // BN
    k5_stats<<<(N_NODES + 255) / 256, 256, 0, stream>>>(outpb, bnsum, bnsq);
    k6_apply<<<(N_NODES + 255) / 256, 256, 0, stream>>>(outpb, bnsum, bnsq,
                                                        gamma, beta, out);
}

// Round 10
// 192.499 us; speedup vs baseline: 12.1246x; 1.0341x over previous
//
#include <hip/hip_runtime.h>
#include <math.h>

#define N_NODES 50000
#define E_EDGES 800000
#define IN_DIM 128
#define HEADS 4
#define OUT_DIM 32
#define HD 128          // HEADS*OUT_DIM
#define LEAKY 0.4f
#define BN_EPS 1e-5f

// bucketed counting sort params: bucket = tgt >> 7 (128 targets/bucket)
#define BSH 7
#define NB ((N_NODES + 127) >> BSH)     // 391
#define FB 196                           // kb_fill blocks
#define FCH 4096                         // edges per kb_fill block
#define PCAP 2560                        // padded bucket capacity (mean 2048, sd 45)
#define SRTCAP 3072                      // LDS staging cap in kb_sort
#define SCCH ((NB + 63) / 64)            // 7: scan chunk per lane

typedef __attribute__((ext_vector_type(8))) short short8;
typedef __attribute__((ext_vector_type(8))) unsigned short us8;
typedef __attribute__((ext_vector_type(4))) float f32x4;

// ---- monotonic float<->uint encoding for atomicMax on floats ----
__device__ __forceinline__ unsigned enc_max(float f) {
    unsigned u = __float_as_uint(f);
    return ((int)u >= 0) ? (u | 0x80000000u) : ~u;
}
__device__ __forceinline__ float dec_max(unsigned u) {
    return (u & 0x80000000u) ? __uint_as_float(u ^ 0x80000000u)
                             : __uint_as_float(~u);
}

__device__ __forceinline__ float leaky(float v) {
    return v > 0.f ? v : LEAKY * v;
}

// fp32 -> bf16 (round-to-nearest-even), finite inputs
__device__ __forceinline__ unsigned short f2bf(float f) {
    unsigned u = __float_as_uint(f);
    u = (u + 0x7FFFu + ((u >> 16) & 1u)) >> 16;
    return (unsigned short)u;
}
__device__ __forceinline__ float bf2f(unsigned short u) {
    return __uint_as_float(((unsigned)u) << 16);
}

// ============================================================
// KB1: bucket the edges into FIXED padded regions (b*PCAP), reserving
// per-block runs with one global atomic per (block,bucket).
// Packed entry: src (16b) | tgt_local (7b) << 16.
// ============================================================
__global__ __launch_bounds__(256) void kb_fill(
    const int* __restrict__ src, const int* __restrict__ tgt,
    int* __restrict__ bcur, int* __restrict__ ebkt)
{
    __shared__ int hist[NB];
    __shared__ int rbase[NB];
    int beg = blockIdx.x * FCH;
    int end = min(beg + FCH, E_EDGES);
    for (int i = threadIdx.x; i < NB; i += 256) hist[i] = 0;
    __syncthreads();
    for (int e = beg + threadIdx.x; e < end; e += 256)
        atomicAdd(&hist[tgt[e] >> BSH], 1);
    __syncthreads();
    for (int i = threadIdx.x; i < NB; i += 256) {
        int c = hist[i];
        if (c) {
            int r = atomicAdd(&bcur[i], c);
            rbase[i] = i * PCAP + min(r, PCAP);
        }
    }
    __syncthreads();
    for (int i = threadIdx.x; i < NB; i += 256) hist[i] = 0;  // reuse as cursor
    __syncthreads();
    for (int e = beg + threadIdx.x; e < end; e += 256) {
        int tv = tgt[e], b = tv >> BSH;
        int off = atomicAdd(&hist[b], 1);
        int idx = rbase[b] + off;
        if (idx < (b + 1) * PCAP)                 // overflow guard (never hits)
            ebkt[idx] = src[e] | ((tv & 127) << 16);
    }
}

// ============================================================
// KB2: fine sort within bucket -> rowptr + esrc (ushort), compacting
// padded region b*PCAP -> contiguous bbase[b]. The 391-entry exclusive
// scan of bucket counts is computed in-block (wave 0, chunked) --
// redundant across blocks but saves a dispatch. Coarse-sorts by
// src-chunk (src>>9) for sliding-window gather locality in k4_pull.
// ============================================================
__global__ __launch_bounds__(256) void kb_sort(
    const int* __restrict__ bcur, const int* __restrict__ ebkt,
    int* __restrict__ rowptr, unsigned short* __restrict__ esrc)
{
    __shared__ int ebl[SRTCAP];
    __shared__ int srt[SRTCAP];
    __shared__ int csc[NB + 1];               // bucket-count scan
    __shared__ int bins[128];                 // 98 chunk bins used
    __shared__ int deg_l[128], excl_l[128], cur_l[128];
    __shared__ int wtot, btot;
    int b    = blockIdx.x;
    int tid  = threadIdx.x;
    int lane = tid & 63, wv = tid >> 6;

    // load counts
    for (int i = tid; i < NB; i += 256) csc[i] = min(bcur[i], PCAP);
    if (tid < 128) { deg_l[tid] = 0; cur_l[tid] = 0; bins[tid] = 0; }
    __syncthreads();
    // wave-0 chunked exclusive scan of csc[0..NB)
    if (tid < 64) {
        int cb = tid * SCCH;
        int loc[SCCH];
        int sum = 0;
#pragma unroll
        for (int k = 0; k < SCCH; k++) {
            int idx = cb + k;
            int v = (idx < NB) ? csc[idx] : 0;
            loc[k] = sum; sum += v;
        }
        int ss = sum;
#pragma unroll
        for (int off = 1; off < 64; off <<= 1) {
            int u = __shfl_up(ss, off, 64);
            if (tid >= off) ss += u;
        }
        int excl = ss - sum;
#pragma unroll
        for (int k = 0; k < SCCH; k++) {
            int idx = cb + k;
            if (idx < NB) csc[idx] = excl + loc[k];
        }
        if (tid == 63) {
            csc[NB] = excl + sum;             // == E_EDGES
            if (b == 0) rowptr[N_NODES] = excl + sum;
        }
    }
    __syncthreads();
    int base_in = b * PCAP;
    int base    = csc[b];
    int cnt     = csc[b + 1] - base;          // <= PCAP <= SRTCAP

    // stage + coarse src-chunk histogram
    for (int j = tid; j < cnt; j += 256) {
        int p = ebkt[base_in + j];
        ebl[j] = p;
        atomicAdd(&bins[(p & 0xFFFF) >> 9], 1);
    }
    __syncthreads();
    {
        int v = (tid < 128) ? bins[tid] : 0;
        int s = v;
#pragma unroll
        for (int off = 1; off < 64; off <<= 1) {
            int u = __shfl_up(s, off, 64);
            if (lane >= off) s += u;
        }
        if (tid == 63) btot = s;
        __syncthreads();
        if (tid < 128) bins[tid] = s - v + ((wv == 1) ? btot : 0);
        __syncthreads();
    }
    for (int j = tid; j < cnt; j += 256) {
        int p = ebl[j];
        int pos = atomicAdd(&bins[(p & 0xFFFF) >> 9], 1);
        srt[pos] = p;
    }
    __syncthreads();
    for (int j = tid; j < cnt; j += 256)
        atomicAdd(&deg_l[srt[j] >> 16], 1);
    __syncthreads();

    // exclusive scan of 128 target degrees
    int v = (tid < 128) ? deg_l[tid] : 0;
    int s = v;
#pragma unroll
    for (int off = 1; off < 64; off <<= 1) {
        int u = __shfl_up(s, off, 64);
        if (lane >= off) s += u;
    }
    if (tid == 63) wtot = s;
    __syncthreads();
    if (tid < 128) {
        int ex = s - v + ((wv == 1) ? wtot : 0);
        excl_l[tid] = ex;
        int node = (b << BSH) + tid;
        if (node < N_NODES) rowptr[node] = base + ex;
    }
    __syncthreads();
    for (int j = tid; j < cnt; j += 256) {
        int p  = srt[j];
        int tl = p >> 16;
        int off = atomicAdd(&cur_l[tl], 1);
        esrc[base + excl_l[tl] + off] = (unsigned short)(p & 0xFFFF);
    }
}

// ============================================================
// K1: h = x @ W via mfma_f32_16x16x32_bf16, fp32 x converted inline.
// W staged into LDS pre-swizzled into B-fragment layout (32 KB).
// Epilogue: h stored as bf16 (hb); fused s/t logit dots.
// ============================================================
__global__ __launch_bounds__(256) void k1_mfma(
    const float* __restrict__ x, const float* __restrict__ W,
    const float* __restrict__ a_src, const float* __restrict__ a_tgt,
    unsigned short* __restrict__ hb, float* __restrict__ s,
    float* __restrict__ t)
{
    __shared__ unsigned short Wl[32 * 64 * 8];   // 32 KB
    const int tid = threadIdx.x;
    for (int idx = tid; idx < 2048; idx += 256) {
        int l  = idx & 63;
        int f  = idx >> 6;
        int nt = f >> 2, kc = f & 3;
        int kbase = kc * 32 + ((l >> 4) << 3);
        int col   = nt * 16 + (l & 15);
        unsigned short* dst = &Wl[idx * 8];
#pragma unroll
        for (int j = 0; j < 8; j++)
            dst[j] = f2bf(W[(kbase + j) * HD + col]);
    }
    __syncthreads();

    const int wave = tid >> 6, lane = tid & 63;
    const int quad = lane >> 4, rl = lane & 15;
    const int row0 = blockIdx.x * 64 + wave * 16;
    const int crow = min(row0 + rl, N_NODES - 1);

    short8 a[4];
    const float* xp = x + (size_t)crow * IN_DIM + quad * 8;
#pragma unroll
    for (int kc = 0; kc < 4; kc++) {
        float4 v0 = *(const float4*)(xp + kc * 32);
        float4 v1 = *(const float4*)(xp + kc * 32 + 4);
        short8 av;
        av[0] = (short)f2bf(v0.x); av[1] = (short)f2bf(v0.y);
        av[2] = (short)f2bf(v0.z); av[3] = (short)f2bf(v0.w);
        av[4] = (short)f2bf(v1.x); av[5] = (short)f2bf(v1.y);
        av[6] = (short)f2bf(v1.z); av[7] = (short)f2bf(v1.w);
        a[kc] = av;
    }

    float asv[8], atv[8];
#pragma unroll
    for (int nt = 0; nt < 8; nt++) {
        asv[nt] = a_src[nt * 16 + rl];
        atv[nt] = a_tgt[nt * 16 + rl];
    }

    float ps[4][4], pt[4][4];   // [head][r]
#pragma unroll
    for (int hh = 0; hh < 4; hh++)
#pragma unroll
        for (int r = 0; r < 4; r++) { ps[hh][r] = 0.f; pt[hh][r] = 0.f; }

#pragma unroll
    for (int nt = 0; nt < 8; nt++) {
        f32x4 acc = {0.f, 0.f, 0.f, 0.f};
#pragma unroll
        for (int kc = 0; kc < 4; kc++) {
            short8 b = *(const short8*)&Wl[((nt * 4 + kc) * 64 + lane) * 8];
            acc = __builtin_amdgcn_mfma_f32_16x16x32_bf16(a[kc], b, acc, 0, 0, 0);
        }
        const int ocol = nt * 16 + rl;
        const int hh   = nt >> 1;
#pragma unroll
        for (int r = 0; r < 4; r++) {
            int orow = row0 + quad * 4 + r;
            if (orow < N_NODES)
                hb[(size_t)orow * HD + ocol] = f2bf(acc[r]);
            ps[hh][r] = fmaf(acc[r], asv[nt], ps[hh][r]);
            pt[hh][r] = fmaf(acc[r], atv[nt], pt[hh][r]);
        }
    }

#pragma unroll
    for (int m = 1; m <= 8; m <<= 1) {
#pragma unroll
        for (int hh = 0; hh < 4; hh++)
#pragma unroll
            for (int r = 0; r < 4; r++) {
                ps[hh][r] += __shfl_xor(ps[hh][r], m, 64);
                pt[hh][r] += __shfl_xor(pt[hh][r], m, 64);
            }
    }
    if (rl == 0) {
#pragma unroll
        for (int r = 0; r < 4; r++) {
            int orow = row0 + quad * 4 + r;
            if (orow < N_NODES) {
#pragma unroll
                for (int hh = 0; hh < 4; hh++) {
                    s[orow * HEADS + hh] = ps[hh][r];
                    t[orow * HEADS + hh] = pt[hh][r];
                }
            }
        }
    }
}

// ============================================================
// K2: per-head max over NODES of s and t separately.
// 32 blocks only: per-address atomic serialization (~11 ns/op) stays ~0.4us.
// ============================================================
#define K2_BLOCKS 32
__global__ __launch_bounds__(256) void k2_nodemax(
    const float* __restrict__ s, const float* __restrict__ t,
    unsigned* __restrict__ smax, unsigned* __restrict__ tmax)
{
    float sm0 = -INFINITY, sm1 = -INFINITY, sm2 = -INFINITY, sm3 = -INFINITY;
    float tm0 = -INFINITY, tm1 = -INFINITY, tm2 = -INFINITY, tm3 = -INFINITY;
    for (int n = blockIdx.x * 256 + threadIdx.x; n < N_NODES;
         n += K2_BLOCKS * 256) {
        float4 s4 = ((const float4*)s)[n];
        float4 t4 = ((const float4*)t)[n];
        sm0 = fmaxf(sm0, s4.x); sm1 = fmaxf(sm1, s4.y);
        sm2 = fmaxf(sm2, s4.z); sm3 = fmaxf(sm3, s4.w);
        tm0 = fmaxf(tm0, t4.x); tm1 = fmaxf(tm1, t4.y);
        tm2 = fmaxf(tm2, t4.z); tm3 = fmaxf(tm3, t4.w);
    }
#pragma unroll
    for (int m = 32; m >= 1; m >>= 1) {
        sm0 = fmaxf(sm0, __shfl_xor(sm0, m, 64));
        sm1 = fmaxf(sm1, __shfl_xor(sm1, m, 64));
        sm2 = fmaxf(sm2, __shfl_xor(sm2, m, 64));
        sm3 = fmaxf(sm3, __shfl_xor(sm3, m, 64));
        tm0 = fmaxf(tm0, __shfl_xor(tm0, m, 64));
        tm1 = fmaxf(tm1, __shfl_xor(tm1, m, 64));
        tm2 = fmaxf(tm2, __shfl_xor(tm2, m, 64));
        tm3 = fmaxf(tm3, __shfl_xor(tm3, m, 64));
    }
    __shared__ float red[4][8];
    int wid = threadIdx.x >> 6;
    if ((threadIdx.x & 63) == 0) {
        red[wid][0] = sm0; red[wid][1] = sm1; red[wid][2] = sm2; red[wid][3] = sm3;
        red[wid][4] = tm0; red[wid][5] = tm1; red[wid][6] = tm2; red[wid][7] = tm3;
    }
    __syncthreads();
    if (threadIdx.x < 8) {
        float v = fmaxf(fmaxf(red[0][threadIdx.x], red[1][threadIdx.x]),
                        fmaxf(red[2][threadIdx.x], red[3][threadIdx.x]));
        unsigned* dst = (threadIdx.x < 4) ? &smax[threadIdx.x]
                                          : &tmax[threadIdx.x - 4];
        atomicMax(dst, enc_max(v));
    }
}

// ============================================================
// K4: pull aggregation. 16 lanes per target node, 8 bf16 ch each (16 B).
// Dual accumulator sets: halves the fma dependency chain and doubles
// outstanding gathers (latency-bound per R7 counters: VALUBusy 27%).
// ============================================================
__global__ __launch_bounds__(256) void k4_pull(
    const int* __restrict__ rowptr, const unsigned short* __restrict__ esrc,
    const float* __restrict__ s, const float* __restrict__ t,
    const unsigned* __restrict__ smax, const unsigned* __restrict__ tmax,
    const unsigned short* __restrict__ hb, unsigned short* __restrict__ outpb)
{
    int g = blockIdx.x * 256 + threadIdx.x;
    int node = g >> 4;
    int lane = g & 15;
    if (node >= N_NODES) return;
    int head = lane >> 2;                 // 4 lanes per head, 8 ch each
    int beg = rowptr[node];
    int end = rowptr[node + 1];
    float mx = leaky(dec_max(smax[head]) + dec_max(tmax[head]));
    float tv = t[node * HEADS + head];

    float p0 = 0.f, p1 = 0.f, p2 = 0.f, p3 = 0.f;
    float p4 = 0.f, p5 = 0.f, p6 = 0.f, p7 = 0.f, psum = 0.f;
    float q0 = 0.f, q1 = 0.f, q2 = 0.f, q3 = 0.f;
    float q4 = 0.f, q5 = 0.f, q6 = 0.f, q7 = 0.f, qsum = 0.f;
    const unsigned short* hbase = hb + lane * 8;
    int j = beg;
    for (; j + 1 < end; j += 2) {
        int si0 = esrc[j];
        int si1 = esrc[j + 1];
        float sv0 = s[si0 * HEADS + head];
        float sv1 = s[si1 * HEADS + head];
        us8 h0 = *(const us8*)(hbase + (size_t)si0 * HD);
        us8 h1 = *(const us8*)(hbase + (size_t)si1 * HD);
        float al0 = __expf(leaky(sv0 + tv) - mx);
        float al1 = __expf(leaky(sv1 + tv) - mx);
        p0 = fmaf(al0, bf2f(h0[0]), p0);  q0 = fmaf(al1, bf2f(h1[0]), q0);
        p1 = fmaf(al0, bf2f(h0[1]), p1);  q1 = fmaf(al1, bf2f(h1[1]), q1);
        p2 = fmaf(al0, bf2f(h0[2]), p2);  q2 = fmaf(al1, bf2f(h1[2]), q2);
        p3 = fmaf(al0, bf2f(h0[3]), p3);  q3 = fmaf(al1, bf2f(h1[3]), q3);
        p4 = fmaf(al0, bf2f(h0[4]), p4);  q4 = fmaf(al1, bf2f(h1[4]), q4);
        p5 = fmaf(al0, bf2f(h0[5]), p5);  q5 = fmaf(al1, bf2f(h1[5]), q5);
        p6 = fmaf(al0, bf2f(h0[6]), p6);  q6 = fmaf(al1, bf2f(h1[6]), q6);
        p7 = fmaf(al0, bf2f(h0[7]), p7);  q7 = fmaf(al1, bf2f(h1[7]), q7);
        psum += al0; qsum += al1;
    }
    if (j < end) {
        int si  = esrc[j];
        float sv = s[si * HEADS + head];
        float a  = __expf(leaky(sv + tv) - mx);
        us8 hv = *(const us8*)(hbase + (size_t)si * HD);
        p0 = fmaf(a, bf2f(hv[0]), p0);
        p1 = fmaf(a, bf2f(hv[1]), p1);
        p2 = fmaf(a, bf2f(hv[2]), p2);
        p3 = fmaf(a, bf2f(hv[3]), p3);
        p4 = fmaf(a, bf2f(hv[4]), p4);
        p5 = fmaf(a, bf2f(hv[5]), p5);
        p6 = fmaf(a, bf2f(hv[6]), p6);
        p7 = fmaf(a, bf2f(hv[7]), p7);
        psum += a;
    }
    float w = 1.0f / (psum + qsum + 1e-16f);
    us8 o;
    o[0] = f2bf((p0 + q0) * w); o[1] = f2bf((p1 + q1) * w);
    o[2] = f2bf((p2 + q2) * w); o[3] = f2bf((p3 + q3) * w);
    o[4] = f2bf((p4 + q4) * w); o[5] = f2bf((p5 + q5) * w);
    o[6] = f2bf((p6 + q6) * w); o[7] = f2bf((p7 + q7) * w);
    *(us8*)(outpb + (size_t)node * HD + lane * 8) = o;
}

// ============================================================
// K5: BN stats from bf16 outp: per-channel sum & sumsq
// ============================================================
__global__ __launch_bounds__(256) void k5_stats(
    const unsigned short* __restrict__ outpb,
    float* __restrict__ bnsum, float* __restrict__ bnsq)
{
    __shared__ float lsum[HD], lsq[HD];
    int c8  = threadIdx.x & 15;          // channel octet
    int grp = threadIdx.x >> 4;          // row subgroup 0..15
    if (threadIdx.x < HD) { lsum[threadIdx.x] = 0.f; lsq[threadIdx.x] = 0.f; }
    __syncthreads();
    int base = blockIdx.x * 256;
    int end  = min(base + 256, N_NODES);
    float sm[8], sq[8];
#pragma unroll
    for (int i = 0; i < 8; i++) { sm[i] = 0.f; sq[i] = 0.f; }
    for (int r = base + grp; r < end; r += 16) {
        us8 v = *(const us8*)(outpb + (size_t)r * HD + c8 * 8);
#pragma unroll
        for (int i = 0; i < 8; i++) {
            float f = bf2f(v[i]);
            sm[i] += f;
            sq[i] = fmaf(f, f, sq[i]);
        }
    }
#pragma unroll
    for (int i = 0; i < 8; i++) {
        atomicAdd(&lsum[c8 * 8 + i], sm[i]);
        atomicAdd(&lsq[c8 * 8 + i], sq[i]);
    }
    __syncthreads();
    if (threadIdx.x < HD) {
        unsafeAtomicAdd(&bnsum[threadIdx.x], lsum[threadIdx.x]);
        unsafeAtomicAdd(&bnsq[threadIdx.x], lsq[threadIdx.x]);
    }
}

// ============================================================
// K6: BN apply (bf16 in, fp32 out) -> d_out
// ============================================================
__global__ __launch_bounds__(256) void k6_apply(
    const unsigned short* __restrict__ outpb,
    const float* __restrict__ bnsum, const float* __restrict__ bnsq,
    const float* __restrict__ gamma, const float* __restrict__ beta,
    float* __restrict__ out)
{
    int c8  = threadIdx.x & 15;
    int grp = threadIdx.x >> 4;
    int base = blockIdx.x * 256;
    int end  = min(base + 256, N_NODES);
    float inv_n = 1.0f / (float)N_NODES;
    float scale[8], shift[8];
#pragma unroll
    for (int i = 0; i < 8; i++) {
        int c = c8 * 8 + i;
        float mean = bnsum[c] * inv_n;
        float var  = bnsq[c] * inv_n - mean * mean;
        float sc   = gamma[c] * rsqrtf(var + BN_EPS);
        scale[i] = sc;
        shift[i] = beta[c] - mean * sc;
    }
    for (int r = base + grp; r < end; r += 16) {
        us8 v = *(const us8*)(outpb + (size_t)r * HD + c8 * 8);
        float4 o0, o1;
        o0.x = fmaf(bf2f(v[0]), scale[0], shift[0]);
        o0.y = fmaf(bf2f(v[1]), scale[1], shift[1]);
        o0.z = fmaf(bf2f(v[2]), scale[2], shift[2]);
        o0.w = fmaf(bf2f(v[3]), scale[3], shift[3]);
        o1.x = fmaf(bf2f(v[4]), scale[4], shift[4]);
        o1.y = fmaf(bf2f(v[5]), scale[5], shift[5]);
        o1.z = fmaf(bf2f(v[6]), scale[6], shift[6]);
        o1.w = fmaf(bf2f(v[7]), scale[7], shift[7]);
        float* op = out + (size_t)r * HD + c8 * 8;
        ((float4*)op)[0] = o0;
        ((float4*)op)[1] = o1;
    }
}

// ============================================================
extern "C" void kernel_launch(void* const* d_in, const int* in_sizes, int n_in,
                              void* d_out, int out_size, void* d_ws, size_t ws_size,
                              hipStream_t stream)
{
    const float* x     = (const float*)d_in[0];
    const float* W     = (const float*)d_in[1];
    const float* a_src = (const float*)d_in[2];
    const float* a_tgt = (const float*)d_in[3];
    const float* gamma = (const float*)d_in[4];
    const float* beta  = (const float*)d_in[5];
    const int*   eidx  = (const int*)d_in[6];
    const int* src = eidx;
    const int* tgt = eidx + E_EDGES;
    float* out = (float*)d_out;

    // workspace layout
    unsigned short* hb    = (unsigned short*)d_ws;          // 6.4M ushort
    float*          s     = (float*)d_ws + 3200000;         // 200K float
    float*          t     = s + (size_t)N_NODES * HEADS;    // 200K float
    unsigned short* outpb = (unsigned short*)(t + (size_t)N_NODES * HEADS); // 6.4M us
    int*            ebkt  = (int*)outpb;                    // NB*PCAP=1.0M int (aliases outpb)
    unsigned short* esrc  = outpb + 6400000;                // 800K ushort
    int*            rowptr= (int*)(esrc + E_EDGES);         // 50,001 int
    // ---- zero-init region (single memset) ----
    int*      bcur  = rowptr + N_NODES + 1;                 // 392
    unsigned* smax  = (unsigned*)(bcur + 392);              // 4
    unsigned* tmax  = smax + 4;                             // 4
    float*    bnsum = (float*)(tmax + 4);                   // 128
    float*    bnsq  = bnsum + HD;                           // 128
    size_t zero_bytes = (392 + 8 + HD + HD) * 4;
    hipMemsetAsync(bcur, 0, zero_bytes, stream);

    // CSR build (padded-bucket counting sort; scan fused into kb_sort)
    kb_fill<<<FB, 256, 0, stream>>>(src, tgt, bcur, ebkt);
    kb_sort<<<NB, 256, 0, stream>>>(bcur, ebkt, rowptr, esrc);

    // GEMM (bf16 MFMA) with fused bf16-h store + s/t logits
    k1_mfma<<<(N_NODES + 63) / 64, 256, 0, stream>>>(x, W, a_src, a_tgt,
                                                     hb, s, t);
    // per-head node max of s,t (upper bound on edge max; shift cancels)
    k2_nodemax<<<K2_BLOCKS, 256, 0, stream>>>(s, t, smax, tmax);
    // pull aggregation (no atomics), bf16 h gather, bf16 out
    long long k4_threads = (long long)N_NODES * 16;
    k4_pull<<<(unsigned)((k4_threads + 255) / 256), 256, 0, stream>>>(
        rowptr, esrc, s, t, smax, tmax, hb, outpb);
    // BN
    k5_stats<<<(N_NODES + 255) / 256, 256, 0, stream>>>(outpb, bnsum, bnsq);
    k6_apply<<<(N_NODES + 255) / 256, 256, 0, stream>>>(outpb, bnsum, bnsq,
                                                        gamma, beta, out);
}